// Round 11
// baseline (1956.506 us; speedup 1.0000x reference)
//
#include <hip/hip_runtime.h>
#include <stdint.h>

#define N_NODES 100000
#define N_EDGES 400000
#define N_GRAPHS 2000
#define C_IN 48
#define HD 128
#define NLAYERS 6
#define BN_EPS 1e-5f
#define NSLOPE 0.01f
#define SB 391   // ceil(N_NODES/256)
#define NREP 8   // stats replication factor

typedef uint16_t u16;
typedef uint32_t u32;
typedef short bf16x8 __attribute__((ext_vector_type(8)));
typedef float f32x4 __attribute__((ext_vector_type(4)));

__device__ __forceinline__ float bf2f_lo(u32 v) { return __uint_as_float(v << 16); }
__device__ __forceinline__ float bf2f_hi(u32 v) { return __uint_as_float(v & 0xffff0000u); }
__device__ __forceinline__ float bf2f(u16 h) { return __uint_as_float(((u32)h) << 16); }
__device__ __forceinline__ u16 f2bf(float f) {
    u32 u = __float_as_uint(f);
    u32 r = (u + 0x7fffu + ((u >> 16) & 1u)) >> 16;
    return (u16)r;
}
__device__ __forceinline__ u32 pack2(float a, float b) {
    return (u32)f2bf(a) | ((u32)f2bf(b) << 16);
}
__device__ __forceinline__ float lrelu(float v) { return v >= 0.f ? v : v * NSLOPE; }

// dtype detection: mode=1 -> float inputs are fp32; mode=0 -> bf16.
__global__ __launch_bounds__(256) void detect_kernel(const u16* __restrict__ x, int* __restrict__ mode) {
    __shared__ int flag;
    if (threadIdx.x == 0) flag = 0;
    __syncthreads();
    int local = 0;
    for (int i = threadIdx.x; i < 16384; i += 256) {
        float a = fabsf(bf2f(x[i]));
        if (!(a < 1e4f)) local = 1;
    }
    if (local) flag = 1;
    __syncthreads();
    if (threadIdx.x == 0) mode[0] = flag;
}

// ---------------- CSR build ----------------
__global__ __launch_bounds__(256) void hist_kernel(const int* __restrict__ dst, int* __restrict__ cnt) {
    int e = blockIdx.x * 256 + threadIdx.x;
    if (e < N_EDGES) atomicAdd(&cnt[dst[e]], 1);
}

__global__ __launch_bounds__(256) void scan1_kernel(const int* __restrict__ cnt, int* __restrict__ bsum) {
    __shared__ int s[256];
    const int t = threadIdx.x;
    const int i = blockIdx.x * 256 + t;
    s[t] = (i < N_NODES) ? cnt[i] : 0;
    __syncthreads();
    for (int d = 128; d > 0; d >>= 1) {
        if (t < d) s[t] += s[t + d];
        __syncthreads();
    }
    if (t == 0) bsum[blockIdx.x] = s[0];
}

__global__ __launch_bounds__(512) void scan2_kernel(int* __restrict__ bsum, int* __restrict__ row_ptr) {
    __shared__ int s[SB];
    const int t = threadIdx.x;
    if (t < SB) s[t] = bsum[t];
    __syncthreads();
    if (t == 0) {
        int run = 0;
        for (int b = 0; b < SB; ++b) { int v = s[b]; s[b] = run; run += v; }
        row_ptr[0] = 0;
    }
    __syncthreads();
    if (t < SB) bsum[t] = s[t];
}

__global__ __launch_bounds__(256) void scan3_kernel(const int* __restrict__ cnt, const int* __restrict__ bsum,
                                                    int* __restrict__ row_ptr) {
    __shared__ int s[256];
    const int t = threadIdx.x;
    const int i = blockIdx.x * 256 + t;
    s[t] = (i < N_NODES) ? cnt[i] : 0;
    __syncthreads();
    if (t == 0) {
        int run = bsum[blockIdx.x];
        for (int j = 0; j < 256; ++j) { run += s[j]; s[j] = run; }
    }
    __syncthreads();
    if (i < N_NODES) row_ptr[i + 1] = s[t];
}

// fill: also writes row_dst (edge -> destination node) for edge-parallel gather
__global__ __launch_bounds__(256) void fill_kernel(const int* __restrict__ src, const int* __restrict__ dst,
                                                   int* __restrict__ cursor, int* __restrict__ col_idx,
                                                   int* __restrict__ row_dst) {
    int e = blockIdx.x * 256 + threadIdx.x;
    if (e < N_EDGES) {
        int d = dst[e];
        int slot = atomicAdd(&cursor[d], 1);
        col_idx[slot] = src[e];
        row_dst[slot] = d;
    }
}

// ---------------- weight pre-pack into MFMA B-fragment layout (bf16) ----------------
__global__ __launch_bounds__(256) void pack_w_kernel(const void* __restrict__ W1a, const void* __restrict__ W1b,
                                                     const void* __restrict__ W2, const int* __restrict__ mode,
                                                     u16* __restrict__ wpack) {
    const int t = blockIdx.x * 256 + threadIdx.x;  // 12*2048 = 24576
    if (t >= 24576) return;
    const int mat = t >> 11;
    const int r = t & 2047;
    const int l = r & 63;
    const int f = r >> 6;
    const int kb = f >> 3, nt = f & 7;
    const int k0 = kb * 32 + (l >> 4) * 8;
    const int n = nt * 16 + (l & 15);
    const int md = *mode;
    u16 vals[8];
    #pragma unroll
    for (int j = 0; j < 8; ++j) {
        const int k = k0 + j;
        float v;
        if (mat == 0) {
            v = (k < C_IN) ? (md ? ((const float*)W1a)[k * HD + n] : bf2f(((const u16*)W1a)[k * HD + n])) : 0.f;
        } else if (mat < 6) {
            const size_t o = (size_t)(mat - 1) * HD * HD + (size_t)k * HD + n;
            v = md ? ((const float*)W1b)[o] : bf2f(((const u16*)W1b)[o]);
        } else {
            const size_t o = (size_t)(mat - 6) * HD * HD + (size_t)k * HD + n;
            v = md ? ((const float*)W2)[o] : bf2f(((const u16*)W2)[o]);
        }
        vals[j] = f2bf(v);
    }
    uint4 o;
    o.x = (u32)vals[0] | ((u32)vals[1] << 16);
    o.y = (u32)vals[2] | ((u32)vals[3] << 16);
    o.z = (u32)vals[4] | ((u32)vals[5] << 16);
    o.w = (u32)vals[6] | ((u32)vals[7] << 16);
    *reinterpret_cast<uint4*>(wpack + (size_t)t * 8) = o;
}

// ---------------- bias pre-pack to f32 ----------------
__global__ __launch_bounds__(256) void pack_b_kernel(const void* __restrict__ b1, const void* __restrict__ b2,
                                                     const int* __restrict__ mode, float* __restrict__ biasf) {
    const int i = blockIdx.x * 256 + threadIdx.x;  // 12*128
    if (i >= 12 * HD) return;
    const int mat = i >> 7, c = i & 127;
    const int md = *mode;
    float v;
    if (mat < 6) v = md ? ((const float*)b1)[mat * HD + c] : bf2f(((const u16*)b1)[mat * HD + c]);
    else         v = md ? ((const float*)b2)[(mat - 6) * HD + c] : bf2f(((const u16*)b2)[(mat - 6) * HD + c]);
    biasf[i] = v;
}

// ---- shared helper: compute BN coef[256]={A,B} in LDS from replicated raw stats ----
__device__ __forceinline__ void coef_to_lds(float* coefs, const float* __restrict__ instats,
                                            const void* __restrict__ gammav, const void* __restrict__ betav,
                                            size_t gelem, int md, int tid) {
    if (tid < 128) {
        float sm = 0.f, sq = 0.f;
        #pragma unroll
        for (int rep = 0; rep < NREP; ++rep) {
            sm += instats[rep * 256 + tid];
            sq += instats[rep * 256 + 128 + tid];
        }
        const float inv_n = 1.0f / (float)N_NODES;
        const float mean = sm * inv_n;
        const float var = fmaxf(sq * inv_n - mean * mean, 0.f);
        const float rs = rsqrtf(var + BN_EPS);
        const float g  = md ? ((const float*)gammav)[gelem + tid] : bf2f(((const u16*)gammav)[gelem + tid]);
        const float be = md ? ((const float*)betav)[gelem + tid]  : bf2f(((const u16*)betav)[gelem + tid]);
        const float A = g * rs;
        coefs[tid] = A;
        coefs[128 + tid] = be - A * mean;
    }
}

// ---- shared epilogue: bias + store + optional stats (acc in registers) ----
template <int STATS>
__device__ __forceinline__ void epilogue_store(f32x4* acc, float (*sred)[128], float (*sqred)[128],
                                               const float* __restrict__ biasf, int m0, int tid,
                                               u16* out, float* __restrict__ stats, int blkid) {
    const int wave = tid >> 6, lane = tid & 63;
    const int quad = lane >> 4, lx = lane & 15;
    const int mrow0 = m0 + wave * 16;
    #pragma unroll
    for (int nt = 0; nt < 8; ++nt) {
        const int n = nt * 16 + lx;
        const float bj = biasf[n];
        float s = 0.f, q = 0.f;
        #pragma unroll
        for (int r = 0; r < 4; ++r) {
            const int m = mrow0 + quad * 4 + r;
            if (m < N_NODES) {
                const float v = acc[nt][r] + bj;
                out[(size_t)m * HD + n] = f2bf(v);
                if (STATS) { s += v; q += v * v; }
            }
        }
        if (STATS) {
            s += __shfl_xor(s, 16); s += __shfl_xor(s, 32);
            q += __shfl_xor(q, 16); q += __shfl_xor(q, 32);
            if (quad == 0) { sred[wave][n] = s; sqred[wave][n] = q; }
        }
    }
    if (STATS) {
        __syncthreads();
        float* sdst = stats + (size_t)(blkid & (NREP - 1)) * 256;
        if (tid < 128) {
            atomicAdd(&sdst[tid], sred[0][tid] + sred[1][tid] + sred[2][tid] + sred[3][tid]);
        } else if (tid < 256) {
            const int c2 = tid - 128;
            atomicAdd(&sdst[128 + c2], sqred[0][c2] + sqred[1][c2] + sqred[2][c2] + sqred[3][c2]);
        }
    }
}

// ---------------- plain MFMA GEMM: BM=64, LDS A-stage, direct-store epilogue ----------------
// TRANS: BN coefs computed in-block (replicated raw instats + gamma/beta), applied while staging.
// IN-PLACE SAFE (out == A): block reads only its own rows.
template <int TRANS, int STATS>
__global__ __launch_bounds__(256) void gemm_mfma(const u16* A, const u16* __restrict__ wp,
                                                 const float* __restrict__ biasf,
                                                 const float* __restrict__ instats,
                                                 const void* __restrict__ gammav, const void* __restrict__ betav,
                                                 size_t gelem, const int* __restrict__ mode,
                                                 u16* out, float* __restrict__ stats) {
    __shared__ u16 Asm[64][136];
    __shared__ float sred[4][128];
    __shared__ float sqred[4][128];
    __shared__ float coefs[256];
    const int tid = threadIdx.x;
    const int m0 = blockIdx.x * 64;
    const int rrow = tid >> 4;   // 0..15
    const int seg = tid & 15;    // cols seg*8..seg*8+7

    if (TRANS) {
        coef_to_lds(coefs, instats, gammav, betav, gelem, *mode, tid);
        __syncthreads();
    }

    {
        float cA[8], cB[8];
        if (TRANS) {
            #pragma unroll
            for (int j = 0; j < 8; ++j) {
                cA[j] = coefs[seg * 8 + j];
                cB[j] = coefs[128 + seg * 8 + j];
            }
        }
        uint4 v[4];
        #pragma unroll
        for (int i = 0; i < 4; ++i) {
            const int gm = m0 + i * 16 + rrow;
            if (gm < N_NODES) v[i] = *reinterpret_cast<const uint4*>(A + (size_t)gm * HD + seg * 8);
            else { v[i].x = 0; v[i].y = 0; v[i].z = 0; v[i].w = 0; }
        }
        #pragma unroll
        for (int i = 0; i < 4; ++i) {
            uint4 o = v[i];
            if (TRANS) {
                u32 w[4] = {o.x, o.y, o.z, o.w};
                #pragma unroll
                for (int p = 0; p < 4; ++p) {
                    const float lo = lrelu(cA[2 * p] * bf2f_lo(w[p]) + cB[2 * p]);
                    const float hi = lrelu(cA[2 * p + 1] * bf2f_hi(w[p]) + cB[2 * p + 1]);
                    w[p] = pack2(lo, hi);
                }
                o.x = w[0]; o.y = w[1]; o.z = w[2]; o.w = w[3];
            }
            *reinterpret_cast<uint4*>(&Asm[i * 16 + rrow][seg * 8]) = o;
        }
    }
    __syncthreads();

    const int wave = tid >> 6, lane = tid & 63;
    const int quad = lane >> 4, lx = lane & 15;
    f32x4 acc[8] = {};
    #pragma unroll 2
    for (int kb = 0; kb < 4; ++kb) {
        bf16x8 bfr[8];
        #pragma unroll
        for (int nt = 0; nt < 8; ++nt)
            bfr[nt] = *reinterpret_cast<const bf16x8*>(wp + (((size_t)(kb * 8 + nt) * 64 + lane) << 3));
        const bf16x8 af = *reinterpret_cast<const bf16x8*>(&Asm[wave * 16 + lx][kb * 32 + quad * 8]);
        #pragma unroll
        for (int nt = 0; nt < 8; ++nt)
            acc[nt] = __builtin_amdgcn_mfma_f32_16x16x32_bf16(af, bfr[nt], acc[nt], 0, 0, 0);
    }
    epilogue_store<STATS>(acc, sred, sqred, biasf, m0, tid, out, stats, blockIdx.x);
}

// ---------------- FUSED gather+BN+lrelu GEMM — EDGE-PARALLEL staging ----------------
// facc[64][132] f32 accumulators in LDS. Phase 1: self rows (BN+lrelu) written.
// Phase 2: block's contiguous CSR edge range distributed round-robin over 16 thread-groups
// (uniform work, no per-node-degree stragglers); each lane transforms 8 cols of the src row
// and atomically adds into facc[dst_local]. Phase 3: MFMA reads facc (cvt to bf16 in reg).
// NOT in-place. STATS on.
__global__ __launch_bounds__(256) void gemm_gather(const u16* __restrict__ U, const int* __restrict__ row_ptr,
                                                   const int* __restrict__ col_idx, const int* __restrict__ row_dst,
                                                   const u16* __restrict__ wp,
                                                   const float* __restrict__ biasf,
                                                   const float* __restrict__ instats,
                                                   const void* __restrict__ gammav, const void* __restrict__ betav,
                                                   size_t gelem, const int* __restrict__ mode,
                                                   u16* __restrict__ out, float* __restrict__ stats) {
    __shared__ float facc[64][132];
    __shared__ float sred[4][128];
    __shared__ float sqred[4][128];
    __shared__ float coefs[256];
    const int tid = threadIdx.x;
    const int m0 = blockIdx.x * 64;
    const int rrow = tid >> 4;   // group id 0..15
    const int seg = tid & 15;    // cols seg*8..+8

    coef_to_lds(coefs, instats, gammav, betav, gelem, *mode, tid);
    __syncthreads();

    float cA[8], cB[8];
    #pragma unroll
    for (int j = 0; j < 8; ++j) {
        cA[j] = coefs[seg * 8 + j];
        cB[j] = coefs[128 + seg * 8 + j];
    }

    // phase 1: self rows
    #pragma unroll
    for (int i = 0; i < 4; ++i) {
        const int gm = m0 + i * 16 + rrow;
        float f[8];
        #pragma unroll
        for (int j = 0; j < 8; ++j) f[j] = 0.f;
        if (gm < N_NODES) {
            const uint4 v = *reinterpret_cast<const uint4*>(U + (size_t)gm * HD + seg * 8);
            const u32 w[4] = {v.x, v.y, v.z, v.w};
            #pragma unroll
            for (int p = 0; p < 4; ++p) {
                f[2 * p]     = lrelu(cA[2 * p] * bf2f_lo(w[p]) + cB[2 * p]);
                f[2 * p + 1] = lrelu(cA[2 * p + 1] * bf2f_hi(w[p]) + cB[2 * p + 1]);
            }
        }
        #pragma unroll
        for (int j = 0; j < 8; ++j) facc[i * 16 + rrow][seg * 8 + j] = f[j];
    }
    __syncthreads();

    // phase 2: edge-parallel gather (uniform distribution over 16 groups)
    {
        const int estart = row_ptr[m0];
        const int mend = (m0 + 64 < N_NODES) ? (m0 + 64) : N_NODES;
        const int eend = row_ptr[mend];
        int e = estart + rrow;
        for (; e + 16 < eend; e += 32) {
            const int e1 = e + 16;
            const int s0 = col_idx[e],  d0 = row_dst[e]  - m0;
            const int s1 = col_idx[e1], d1 = row_dst[e1] - m0;
            const uint4 v0 = *reinterpret_cast<const uint4*>(U + (size_t)s0 * HD + seg * 8);
            const uint4 v1 = *reinterpret_cast<const uint4*>(U + (size_t)s1 * HD + seg * 8);
            const u32 w0[4] = {v0.x, v0.y, v0.z, v0.w};
            const u32 w1[4] = {v1.x, v1.y, v1.z, v1.w};
            #pragma unroll
            for (int p = 0; p < 4; ++p) {
                atomicAdd(&facc[d0][seg * 8 + 2 * p],     lrelu(cA[2 * p] * bf2f_lo(w0[p]) + cB[2 * p]));
                atomicAdd(&facc[d0][seg * 8 + 2 * p + 1], lrelu(cA[2 * p + 1] * bf2f_hi(w0[p]) + cB[2 * p + 1]));
            }
            #pragma unroll
            for (int p = 0; p < 4; ++p) {
                atomicAdd(&facc[d1][seg * 8 + 2 * p],     lrelu(cA[2 * p] * bf2f_lo(w1[p]) + cB[2 * p]));
                atomicAdd(&facc[d1][seg * 8 + 2 * p + 1], lrelu(cA[2 * p + 1] * bf2f_hi(w1[p]) + cB[2 * p + 1]));
            }
        }
        if (e < eend) {
            const int s0 = col_idx[e], d0 = row_dst[e] - m0;
            const uint4 v0 = *reinterpret_cast<const uint4*>(U + (size_t)s0 * HD + seg * 8);
            const u32 w0[4] = {v0.x, v0.y, v0.z, v0.w};
            #pragma unroll
            for (int p = 0; p < 4; ++p) {
                atomicAdd(&facc[d0][seg * 8 + 2 * p],     lrelu(cA[2 * p] * bf2f_lo(w0[p]) + cB[2 * p]));
                atomicAdd(&facc[d0][seg * 8 + 2 * p + 1], lrelu(cA[2 * p + 1] * bf2f_hi(w0[p]) + cB[2 * p + 1]));
            }
        }
    }
    __syncthreads();

    // phase 3: MFMA from facc (cvt f32 -> bf16 in registers)
    const int wave = tid >> 6, lane = tid & 63;
    const int quad = lane >> 4, lx = lane & 15;
    f32x4 acc[8] = {};
    #pragma unroll 2
    for (int kb = 0; kb < 4; ++kb) {
        bf16x8 bfr[8];
        #pragma unroll
        for (int nt = 0; nt < 8; ++nt)
            bfr[nt] = *reinterpret_cast<const bf16x8*>(wp + (((size_t)(kb * 8 + nt) * 64 + lane) << 3));
        const int row = wave * 16 + lx;
        const int k0 = kb * 32 + quad * 8;
        const float4 a0 = *reinterpret_cast<const float4*>(&facc[row][k0]);
        const float4 a1 = *reinterpret_cast<const float4*>(&facc[row][k0 + 4]);
        bf16x8 af;
        af[0] = (short)f2bf(a0.x); af[1] = (short)f2bf(a0.y);
        af[2] = (short)f2bf(a0.z); af[3] = (short)f2bf(a0.w);
        af[4] = (short)f2bf(a1.x); af[5] = (short)f2bf(a1.y);
        af[6] = (short)f2bf(a1.z); af[7] = (short)f2bf(a1.w);
        #pragma unroll
        for (int nt = 0; nt < 8; ++nt)
            acc[nt] = __builtin_amdgcn_mfma_f32_16x16x32_bf16(af, bfr[nt], acc[nt], 0, 0, 0);
    }
    epilogue_store<1>(acc, sred, sqred, biasf, m0, tid, out, stats, blockIdx.x);
}

// ---------------- FUSED layer-0: gather over x (C_IN cols, no BN) + GEMM (r10 proven) ----------------
__global__ __launch_bounds__(256) void gemm_gather0(const void* __restrict__ xv, const int* __restrict__ row_ptr,
                                                    const int* __restrict__ col_idx, const u16* __restrict__ wp,
                                                    const float* __restrict__ biasf, const int* __restrict__ mode,
                                                    u16* __restrict__ out, float* __restrict__ stats) {
    __shared__ u16 Asm[64][136];
    __shared__ float sred[4][128];
    __shared__ float sqred[4][128];
    const int tid = threadIdx.x;
    const int m0 = blockIdx.x * 64;
    const int rrow = tid >> 4;
    const int seg = tid & 15;          // segs 0..5 carry data (48 cols), 6..15 zero
    const int md = *mode;
    const bool act = seg < 6;

    for (int i = 0; i < 4; ++i) {
        const int gm = m0 + i * 16 + rrow;
        float a[8];
        #pragma unroll
        for (int j = 0; j < 8; ++j) a[j] = 0.f;
        if (gm < N_NODES && act) {
            if (md) {
                const float* xf = (const float*)xv + (size_t)gm * C_IN + seg * 8;
                const float4 v0 = reinterpret_cast<const float4*>(xf)[0];
                const float4 v1 = reinterpret_cast<const float4*>(xf)[1];
                a[0] = v0.x; a[1] = v0.y; a[2] = v0.z; a[3] = v0.w;
                a[4] = v1.x; a[5] = v1.y; a[6] = v1.z; a[7] = v1.w;
            } else {
                const uint4 v = *reinterpret_cast<const uint4*>((const u16*)xv + (size_t)gm * C_IN + seg * 8);
                const u32 w[4] = {v.x, v.y, v.z, v.w};
                #pragma unroll
                for (int p = 0; p < 4; ++p) { a[2 * p] = bf2f_lo(w[p]); a[2 * p + 1] = bf2f_hi(w[p]); }
            }
        }
        if (gm < N_NODES) {
            const int s = row_ptr[gm];
            const int deg = row_ptr[gm + 1] - s;
            for (int t = 0; t < deg; t += 2) {
                const int id0 = col_idx[s + t];
                const bool h1 = (t + 1) < deg;
                const int id1 = h1 ? col_idx[s + t + 1] : 0;
                if (act) {
                    if (md) {
                        const float* p0 = (const float*)xv + (size_t)id0 * C_IN + seg * 8;
                        const float4 u0 = reinterpret_cast<const float4*>(p0)[0];
                        const float4 u1 = reinterpret_cast<const float4*>(p0)[1];
                        a[0] += u0.x; a[1] += u0.y; a[2] += u0.z; a[3] += u0.w;
                        a[4] += u1.x; a[5] += u1.y; a[6] += u1.z; a[7] += u1.w;
                        if (h1) {
                            const float* p1 = (const float*)xv + (size_t)id1 * C_IN + seg * 8;
                            const float4 t0 = reinterpret_cast<const float4*>(p1)[0];
                            const float4 t1 = reinterpret_cast<const float4*>(p1)[1];
                            a[0] += t0.x; a[1] += t0.y; a[2] += t0.z; a[3] += t0.w;
                            a[4] += t1.x; a[5] += t1.y; a[6] += t1.z; a[7] += t1.w;
                        }
                    } else {
                        const uint4 r0 = *reinterpret_cast<const uint4*>((const u16*)xv + (size_t)id0 * C_IN + seg * 8);
                        const u32 w0[4] = {r0.x, r0.y, r0.z, r0.w};
                        #pragma unroll
                        for (int p = 0; p < 4; ++p) { a[2 * p] += bf2f_lo(w0[p]); a[2 * p + 1] += bf2f_hi(w0[p]); }
                        if (h1) {
                            const uint4 r1 = *reinterpret_cast<const uint4*>((const u16*)xv + (size_t)id1 * C_IN + seg * 8);
                            const u32 w1[4] = {r1.x, r1.y, r1.z, r1.w};
                            #pragma unroll
                            for (int p = 0; p < 4; ++p) { a[2 * p] += bf2f_lo(w1[p]); a[2 * p + 1] += bf2f_hi(w1[p]); }
                        }
                    }
                }
            }
        }
        uint4 o;
        o.x = pack2(a[0], a[1]); o.y = pack2(a[2], a[3]);
        o.z = pack2(a[4], a[5]); o.w = pack2(a[6], a[7]);
        *reinterpret_cast<uint4*>(&Asm[i * 16 + rrow][seg * 8]) = o;
    }
    __syncthreads();

    const int wave = tid >> 6, lane = tid & 63;
    const int quad = lane >> 4, lx = lane & 15;
    f32x4 acc[8] = {};
    #pragma unroll 2
    for (int kb = 0; kb < 4; ++kb) {
        bf16x8 bfr[8];
        #pragma unroll
        for (int nt = 0; nt < 8; ++nt)
            bfr[nt] = *reinterpret_cast<const bf16x8*>(wp + (((size_t)(kb * 8 + nt) * 64 + lane) << 3));
        const bf16x8 af = *reinterpret_cast<const bf16x8*>(&Asm[wave * 16 + lx][kb * 32 + quad * 8]);
        #pragma unroll
        for (int nt = 0; nt < 8; ++nt)
            acc[nt] = __builtin_amdgcn_mfma_f32_16x16x32_bf16(af, bfr[nt], acc[nt], 0, 0, 0);
    }
    epilogue_store<1>(acc, sred, sqred, biasf, m0, tid, out, stats, blockIdx.x);
}

// ---------------- pooling: wave per graph, uint4 row loads, quad-parallel rows ----------------
__global__ __launch_bounds__(256) void pool_kernel(const u16* __restrict__ hf, const int* __restrict__ batch,
                                                   const int* __restrict__ mode, float* __restrict__ emb,
                                                   void* __restrict__ outv) {
    const int wave = threadIdx.x >> 6, lane = threadIdx.x & 63;
    const int g = blockIdx.x * 4 + wave;
    if (g >= N_GRAPHS) return;
    const int md = *mode;
    const int quad = lane >> 4, c = lane & 15;
    int lo = 0, hi = N_NODES;
    while (lo < hi) { int m = (lo + hi) >> 1; if (batch[m] < g) lo = m + 1; else hi = m; }
    const int s = lo;
    hi = N_NODES;
    while (lo < hi) { int m = (lo + hi) >> 1; if (batch[m] < g + 1) lo = m + 1; else hi = m; }
    const int e = lo;
    const int cnt = e - s;
    float sum[8], mx[8];
    #pragma unroll
    for (int j = 0; j < 8; ++j) { sum[j] = 0.f; mx[j] = -INFINITY; }
    for (int n = s + quad; n < e; n += 4) {
        const uint4 v = *reinterpret_cast<const uint4*>(hf + (size_t)n * HD + c * 8);
        const u32 w[4] = {v.x, v.y, v.z, v.w};
        #pragma unroll
        for (int p = 0; p < 4; ++p) {
            const float f0 = bf2f_lo(w[p]), f1 = bf2f_hi(w[p]);
            sum[2 * p] += f0; sum[2 * p + 1] += f1;
            mx[2 * p] = fmaxf(mx[2 * p], f0); mx[2 * p + 1] = fmaxf(mx[2 * p + 1], f1);
        }
    }
    #pragma unroll
    for (int j = 0; j < 8; ++j) {
        sum[j] += __shfl_xor(sum[j], 16); sum[j] += __shfl_xor(sum[j], 32);
        mx[j] = fmaxf(mx[j], __shfl_xor(mx[j], 16));
        mx[j] = fmaxf(mx[j], __shfl_xor(mx[j], 32));
    }
    if (quad == 0) {
        const float invc = 1.0f / (float)max(cnt, 1);
        const size_t base = (size_t)N_GRAPHS * 3 + (size_t)g * 256;
        #pragma unroll
        for (int j = 0; j < 8; ++j) {
            const float mean = sum[j] * invc;
            const float m2 = (cnt == 0) ? 0.f : mx[j];
            const int col = c * 8 + j;
            emb[(size_t)g * 256 + col] = mean;
            emb[(size_t)g * 256 + 128 + col] = m2;
            if (md) {
                ((float*)outv)[base + col] = mean;
                ((float*)outv)[base + 128 + col] = m2;
            } else {
                ((u16*)outv)[base + col] = f2bf(mean);
                ((u16*)outv)[base + 128 + col] = f2bf(m2);
            }
        }
    }
}

__global__ __launch_bounds__(64) void final_kernel(const float* __restrict__ emb, const void* __restrict__ fcwv,
                                                   const void* __restrict__ fcbv, const void* __restrict__ fc2wv,
                                                   const void* __restrict__ fc2bv, const int* __restrict__ mode,
                                                   void* __restrict__ outv) {
    __shared__ float es[256];
    __shared__ float hs[64];
    const int g = blockIdx.x, t = threadIdx.x;
    const int md = *mode;
    reinterpret_cast<float4*>(es)[t] = reinterpret_cast<const float4*>(emb + (size_t)g * 256)[t];
    __syncthreads();
    float acc = md ? ((const float*)fcbv)[t] : bf2f(((const u16*)fcbv)[t]);
    if (md) {
        const float* w = (const float*)fcwv;
        #pragma unroll 8
        for (int k = 0; k < 256; ++k) acc += es[k] * w[k * 64 + t];
    } else {
        const u16* w = (const u16*)fcwv;
        #pragma unroll 8
        for (int k = 0; k < 256; ++k) acc += es[k] * bf2f(w[k * 64 + t]);
    }
    hs[t] = lrelu(acc);
    __syncthreads();
    if (t < 3) {
        float o = md ? ((const float*)fc2bv)[t] : bf2f(((const u16*)fc2bv)[t]);
        if (md) {
            const float* w = (const float*)fc2wv;
            #pragma unroll 8
            for (int j = 0; j < 64; ++j) o += hs[j] * w[j * 3 + t];
            ((float*)outv)[(size_t)g * 3 + t] = o;
        } else {
            const u16* w = (const u16*)fc2wv;
            #pragma unroll 8
            for (int j = 0; j < 64; ++j) o += hs[j] * bf2f(w[j * 3 + t]);
            ((u16*)outv)[(size_t)g * 3 + t] = f2bf(o);
        }
    }
}

// ---------------- launch ----------------
static inline size_t align256(size_t x) { return (x + 255) & ~(size_t)255; }

extern "C" void kernel_launch(void* const* d_in, const int* in_sizes, int n_in,
                              void* d_out, int out_size, void* d_ws, size_t ws_size,
                              hipStream_t stream) {
    (void)in_sizes; (void)n_in; (void)out_size; (void)ws_size;
    const void* x    = d_in[0];
    const void* W1a  = d_in[2];
    const void* W1b  = d_in[3];
    const void* b1   = d_in[4];
    const void* g1   = d_in[5];
    const void* be1  = d_in[6];
    const void* W2   = d_in[7];
    const void* b2   = d_in[8];
    const void* gn   = d_in[9];
    const void* bnb  = d_in[10];
    const void* fcw  = d_in[11];
    const void* fcb  = d_in[12];
    const void* fc2w = d_in[13];
    const void* fc2b = d_in[14];
    const int* ei    = (const int*)d_in[15];
    const int* batch = (const int*)d_in[16];

    char* p = (char*)d_ws;
    size_t off = 0;
    u16* zb = (u16*)(p + off); off += align256((size_t)N_NODES * HD * 2);
    u16* hb = (u16*)(p + off); off += align256((size_t)N_NODES * HD * 2);
    u16* wpack = (u16*)(p + off); off += align256((size_t)12 * HD * HD * 2);
    float* biasf = (float*)(p + off); off += align256((size_t)12 * HD * 4);
    float* emb = (float*)(p + off); off += align256((size_t)N_GRAPHS * 256 * 4);
    int* row_ptr = (int*)(p + off); off += align256((size_t)(N_NODES + 1) * 4);
    int* cursor = (int*)(p + off); off += align256((size_t)N_NODES * 4);
    int* col_idx = (int*)(p + off); off += align256((size_t)N_EDGES * 4);
    int* row_dst = (int*)(p + off); off += align256((size_t)N_EDGES * 4);
    int* bsum = (int*)(p + off); off += align256((size_t)SB * 4);
    float* statsAll = (float*)(p + off); off += align256((size_t)12 * NREP * 256 * 4);
    int* mode = (int*)(p + off); off += align256(4);

    const int EB = (N_EDGES + 255) / 256;
    const int GBM = (N_NODES + 63) / 64;     // 1563

    detect_kernel<<<1, 256, 0, stream>>>((const u16*)x, mode);

    hipMemsetAsync(cursor, 0, (size_t)N_NODES * 4, stream);
    hipMemsetAsync(statsAll, 0, (size_t)12 * NREP * 256 * 4, stream);
    hist_kernel<<<EB, 256, 0, stream>>>(ei + N_EDGES, cursor);
    scan1_kernel<<<SB, 256, 0, stream>>>(cursor, bsum);
    scan2_kernel<<<1, 512, 0, stream>>>(bsum, row_ptr);
    scan3_kernel<<<SB, 256, 0, stream>>>(cursor, bsum, row_ptr);
    hipMemcpyAsync(cursor, row_ptr, (size_t)N_NODES * 4, hipMemcpyDeviceToDevice, stream);
    fill_kernel<<<EB, 256, 0, stream>>>(ei, ei + N_EDGES, cursor, col_idx, row_dst);
    pack_w_kernel<<<96, 256, 0, stream>>>(W1a, W1b, W2, mode, wpack);
    pack_b_kernel<<<6, 256, 0, stream>>>(b1, b2, mode, biasf);

    u16* cur = zb;
    u16* oth = hb;
    for (int l = 0; l < NLAYERS; ++l) {
        float* statsA = statsAll + (size_t)l * NREP * 256;
        float* statsB = statsAll + (size_t)(6 + l) * NREP * 256;
        float* statsBprev = statsAll + (size_t)(6 + l - 1) * NREP * 256;
        if (l == 0) {
            // fused gather(x) + gemm1 (no BN on input): x -> cur
            gemm_gather0<<<GBM, 256, 0, stream>>>(x, row_ptr, col_idx, wpack,
                                                  biasf, mode, cur, statsA);
        } else {
            // fused edge-parallel gather+BN(outer,l-1)+lrelu + gemm1: cur -> oth (not in-place)
            gemm_gather<<<GBM, 256, 0, stream>>>(cur, row_ptr, col_idx, row_dst,
                                                 wpack + (size_t)l * HD * HD,
                                                 biasf + (size_t)l * HD, statsBprev, gn, bnb,
                                                 (size_t)(l - 1) * HD, mode, oth, statsA);
            u16* t = cur; cur = oth; oth = t;
        }
        if (l < NLAYERS - 1) {
            gemm_mfma<1, 1><<<GBM, 256, 0, stream>>>(cur, wpack + (size_t)(6 + l) * HD * HD,
                                                     biasf + (size_t)(6 + l) * HD, statsA, g1, be1,
                                                     (size_t)l * HD, mode, cur, statsB);
        } else {
            gemm_mfma<1, 0><<<GBM, 256, 0, stream>>>(cur, wpack + (size_t)(6 + l) * HD * HD,
                                                     biasf + (size_t)(6 + l) * HD, statsA, g1, be1,
                                                     (size_t)l * HD, mode, cur, nullptr);
        }
    }

    pool_kernel<<<(N_GRAPHS + 3) / 4, 256, 0, stream>>>(cur, batch, mode, emb, d_out);
    final_kernel<<<N_GRAPHS, 64, 0, stream>>>(emb, fcw, fcb, fc2w, fc2b, mode, d_out);
}

// Round 12
// 680.103 us; speedup vs baseline: 2.8768x; 2.8768x over previous
//
#include <hip/hip_runtime.h>
#include <stdint.h>

#define N_NODES 100000
#define N_EDGES 400000
#define N_GRAPHS 2000
#define C_IN 48
#define HD 128
#define NLAYERS 6
#define BN_EPS 1e-5f
#define NSLOPE 0.01f
#define SB 391   // ceil(N_NODES/256)
#define NREP 8   // stats replication factor

typedef uint16_t u16;
typedef uint32_t u32;
typedef short bf16x8 __attribute__((ext_vector_type(8)));
typedef float f32x4 __attribute__((ext_vector_type(4)));

__device__ __forceinline__ float bf2f_lo(u32 v) { return __uint_as_float(v << 16); }
__device__ __forceinline__ float bf2f_hi(u32 v) { return __uint_as_float(v & 0xffff0000u); }
__device__ __forceinline__ float bf2f(u16 h) { return __uint_as_float(((u32)h) << 16); }
__device__ __forceinline__ u16 f2bf(float f) {
    u32 u = __float_as_uint(f);
    u32 r = (u + 0x7fffu + ((u >> 16) & 1u)) >> 16;
    return (u16)r;
}
__device__ __forceinline__ u32 pack2(float a, float b) {
    return (u32)f2bf(a) | ((u32)f2bf(b) << 16);
}
__device__ __forceinline__ float lrelu(float v) { return v >= 0.f ? v : v * NSLOPE; }

// dtype detection: mode=1 -> float inputs are fp32; mode=0 -> bf16.
__global__ __launch_bounds__(256) void detect_kernel(const u16* __restrict__ x, int* __restrict__ mode) {
    __shared__ int flag;
    if (threadIdx.x == 0) flag = 0;
    __syncthreads();
    int local = 0;
    for (int i = threadIdx.x; i < 16384; i += 256) {
        float a = fabsf(bf2f(x[i]));
        if (!(a < 1e4f)) local = 1;
    }
    if (local) flag = 1;
    __syncthreads();
    if (threadIdx.x == 0) mode[0] = flag;
}

// ---------------- CSR build ----------------
__global__ __launch_bounds__(256) void hist_kernel(const int* __restrict__ dst, int* __restrict__ cnt) {
    int e = blockIdx.x * 256 + threadIdx.x;
    if (e < N_EDGES) atomicAdd(&cnt[dst[e]], 1);
}

__global__ __launch_bounds__(256) void scan1_kernel(const int* __restrict__ cnt, int* __restrict__ bsum) {
    __shared__ int s[256];
    const int t = threadIdx.x;
    const int i = blockIdx.x * 256 + t;
    s[t] = (i < N_NODES) ? cnt[i] : 0;
    __syncthreads();
    for (int d = 128; d > 0; d >>= 1) {
        if (t < d) s[t] += s[t + d];
        __syncthreads();
    }
    if (t == 0) bsum[blockIdx.x] = s[0];
}

__global__ __launch_bounds__(512) void scan2_kernel(int* __restrict__ bsum, int* __restrict__ row_ptr) {
    __shared__ int s[SB];
    const int t = threadIdx.x;
    if (t < SB) s[t] = bsum[t];
    __syncthreads();
    if (t == 0) {
        int run = 0;
        for (int b = 0; b < SB; ++b) { int v = s[b]; s[b] = run; run += v; }
        row_ptr[0] = 0;
    }
    __syncthreads();
    if (t < SB) bsum[t] = s[t];
}

__global__ __launch_bounds__(256) void scan3_kernel(const int* __restrict__ cnt, const int* __restrict__ bsum,
                                                    int* __restrict__ row_ptr) {
    __shared__ int s[256];
    const int t = threadIdx.x;
    const int i = blockIdx.x * 256 + t;
    s[t] = (i < N_NODES) ? cnt[i] : 0;
    __syncthreads();
    if (t == 0) {
        int run = bsum[blockIdx.x];
        for (int j = 0; j < 256; ++j) { run += s[j]; s[j] = run; }
    }
    __syncthreads();
    if (i < N_NODES) row_ptr[i + 1] = s[t];
}

__global__ __launch_bounds__(256) void fill_kernel(const int* __restrict__ src, const int* __restrict__ dst,
                                                   int* __restrict__ cursor, int* __restrict__ col_idx) {
    int e = blockIdx.x * 256 + threadIdx.x;
    if (e < N_EDGES) {
        int d = dst[e];
        int slot = atomicAdd(&cursor[d], 1);
        col_idx[slot] = src[e];
    }
}

// ---------------- weight pre-pack into MFMA B-fragment layout (bf16) ----------------
__global__ __launch_bounds__(256) void pack_w_kernel(const void* __restrict__ W1a, const void* __restrict__ W1b,
                                                     const void* __restrict__ W2, const int* __restrict__ mode,
                                                     u16* __restrict__ wpack) {
    const int t = blockIdx.x * 256 + threadIdx.x;  // 12*2048 = 24576
    if (t >= 24576) return;
    const int mat = t >> 11;
    const int r = t & 2047;
    const int l = r & 63;
    const int f = r >> 6;
    const int kb = f >> 3, nt = f & 7;
    const int k0 = kb * 32 + (l >> 4) * 8;
    const int n = nt * 16 + (l & 15);
    const int md = *mode;
    u16 vals[8];
    #pragma unroll
    for (int j = 0; j < 8; ++j) {
        const int k = k0 + j;
        float v;
        if (mat == 0) {
            v = (k < C_IN) ? (md ? ((const float*)W1a)[k * HD + n] : bf2f(((const u16*)W1a)[k * HD + n])) : 0.f;
        } else if (mat < 6) {
            const size_t o = (size_t)(mat - 1) * HD * HD + (size_t)k * HD + n;
            v = md ? ((const float*)W1b)[o] : bf2f(((const u16*)W1b)[o]);
        } else {
            const size_t o = (size_t)(mat - 6) * HD * HD + (size_t)k * HD + n;
            v = md ? ((const float*)W2)[o] : bf2f(((const u16*)W2)[o]);
        }
        vals[j] = f2bf(v);
    }
    uint4 o;
    o.x = (u32)vals[0] | ((u32)vals[1] << 16);
    o.y = (u32)vals[2] | ((u32)vals[3] << 16);
    o.z = (u32)vals[4] | ((u32)vals[5] << 16);
    o.w = (u32)vals[6] | ((u32)vals[7] << 16);
    *reinterpret_cast<uint4*>(wpack + (size_t)t * 8) = o;
}

// ---------------- bias pre-pack to f32 ----------------
__global__ __launch_bounds__(256) void pack_b_kernel(const void* __restrict__ b1, const void* __restrict__ b2,
                                                     const int* __restrict__ mode, float* __restrict__ biasf) {
    const int i = blockIdx.x * 256 + threadIdx.x;  // 12*128
    if (i >= 12 * HD) return;
    const int mat = i >> 7, c = i & 127;
    const int md = *mode;
    float v;
    if (mat < 6) v = md ? ((const float*)b1)[mat * HD + c] : bf2f(((const u16*)b1)[mat * HD + c]);
    else         v = md ? ((const float*)b2)[(mat - 6) * HD + c] : bf2f(((const u16*)b2)[(mat - 6) * HD + c]);
    biasf[i] = v;
}

// ---- shared helper: compute BN coef[256]={A,B} in LDS from replicated raw stats ----
__device__ __forceinline__ void coef_to_lds(float* coefs, const float* __restrict__ instats,
                                            const void* __restrict__ gammav, const void* __restrict__ betav,
                                            size_t gelem, int md, int tid) {
    if (tid < 128) {
        float sm = 0.f, sq = 0.f;
        #pragma unroll
        for (int rep = 0; rep < NREP; ++rep) {
            sm += instats[rep * 256 + tid];
            sq += instats[rep * 256 + 128 + tid];
        }
        const float inv_n = 1.0f / (float)N_NODES;
        const float mean = sm * inv_n;
        const float var = fmaxf(sq * inv_n - mean * mean, 0.f);
        const float rs = rsqrtf(var + BN_EPS);
        const float g  = md ? ((const float*)gammav)[gelem + tid] : bf2f(((const u16*)gammav)[gelem + tid]);
        const float be = md ? ((const float*)betav)[gelem + tid]  : bf2f(((const u16*)betav)[gelem + tid]);
        const float A = g * rs;
        coefs[tid] = A;
        coefs[128 + tid] = be - A * mean;
    }
}

// ---- shared epilogue: bias + store + optional stats (acc in registers) ----
template <int STATS>
__device__ __forceinline__ void epilogue_store(f32x4* acc, float (*sred)[128], float (*sqred)[128],
                                               const float* __restrict__ biasf, int m0, int tid,
                                               u16* out, float* __restrict__ stats, int blkid) {
    const int wave = tid >> 6, lane = tid & 63;
    const int quad = lane >> 4, lx = lane & 15;
    const int mrow0 = m0 + wave * 16;
    #pragma unroll
    for (int nt = 0; nt < 8; ++nt) {
        const int n = nt * 16 + lx;
        const float bj = biasf[n];
        float s = 0.f, q = 0.f;
        #pragma unroll
        for (int r = 0; r < 4; ++r) {
            const int m = mrow0 + quad * 4 + r;
            if (m < N_NODES) {
                const float v = acc[nt][r] + bj;
                out[(size_t)m * HD + n] = f2bf(v);
                if (STATS) { s += v; q += v * v; }
            }
        }
        if (STATS) {
            s += __shfl_xor(s, 16); s += __shfl_xor(s, 32);
            q += __shfl_xor(q, 16); q += __shfl_xor(q, 32);
            if (quad == 0) { sred[wave][n] = s; sqred[wave][n] = q; }
        }
    }
    if (STATS) {
        __syncthreads();
        float* sdst = stats + (size_t)(blkid & (NREP - 1)) * 256;
        if (tid < 128) {
            atomicAdd(&sdst[tid], sred[0][tid] + sred[1][tid] + sred[2][tid] + sred[3][tid]);
        } else if (tid < 256) {
            const int c2 = tid - 128;
            atomicAdd(&sdst[128 + c2], sqred[0][c2] + sqred[1][c2] + sqred[2][c2] + sqred[3][c2]);
        }
    }
}

// ---------------- plain MFMA GEMM: BM=64, LDS A-stage, direct-store epilogue ----------------
// TRANS: BN coefs computed in-block (replicated raw instats + gamma/beta), applied while staging.
// IN-PLACE SAFE (out == A): block reads only its own rows.
template <int TRANS, int STATS>
__global__ __launch_bounds__(256) void gemm_mfma(const u16* A, const u16* __restrict__ wp,
                                                 const float* __restrict__ biasf,
                                                 const float* __restrict__ instats,
                                                 const void* __restrict__ gammav, const void* __restrict__ betav,
                                                 size_t gelem, const int* __restrict__ mode,
                                                 u16* out, float* __restrict__ stats) {
    __shared__ u16 Asm[64][136];
    __shared__ float sred[4][128];
    __shared__ float sqred[4][128];
    __shared__ float coefs[256];
    const int tid = threadIdx.x;
    const int m0 = blockIdx.x * 64;
    const int rrow = tid >> 4;   // 0..15
    const int seg = tid & 15;    // cols seg*8..seg*8+7

    if (TRANS) {
        coef_to_lds(coefs, instats, gammav, betav, gelem, *mode, tid);
        __syncthreads();
    }

    {
        float cA[8], cB[8];
        if (TRANS) {
            #pragma unroll
            for (int j = 0; j < 8; ++j) {
                cA[j] = coefs[seg * 8 + j];
                cB[j] = coefs[128 + seg * 8 + j];
            }
        }
        uint4 v[4];
        #pragma unroll
        for (int i = 0; i < 4; ++i) {
            const int gm = m0 + i * 16 + rrow;
            if (gm < N_NODES) v[i] = *reinterpret_cast<const uint4*>(A + (size_t)gm * HD + seg * 8);
            else { v[i].x = 0; v[i].y = 0; v[i].z = 0; v[i].w = 0; }
        }
        #pragma unroll
        for (int i = 0; i < 4; ++i) {
            uint4 o = v[i];
            if (TRANS) {
                u32 w[4] = {o.x, o.y, o.z, o.w};
                #pragma unroll
                for (int p = 0; p < 4; ++p) {
                    const float lo = lrelu(cA[2 * p] * bf2f_lo(w[p]) + cB[2 * p]);
                    const float hi = lrelu(cA[2 * p + 1] * bf2f_hi(w[p]) + cB[2 * p + 1]);
                    w[p] = pack2(lo, hi);
                }
                o.x = w[0]; o.y = w[1]; o.z = w[2]; o.w = w[3];
            }
            *reinterpret_cast<uint4*>(&Asm[i * 16 + rrow][seg * 8]) = o;
        }
    }
    __syncthreads();

    const int wave = tid >> 6, lane = tid & 63;
    const int quad = lane >> 4, lx = lane & 15;
    f32x4 acc[8] = {};
    #pragma unroll 2
    for (int kb = 0; kb < 4; ++kb) {
        bf16x8 bfr[8];
        #pragma unroll
        for (int nt = 0; nt < 8; ++nt)
            bfr[nt] = *reinterpret_cast<const bf16x8*>(wp + (((size_t)(kb * 8 + nt) * 64 + lane) << 3));
        const bf16x8 af = *reinterpret_cast<const bf16x8*>(&Asm[wave * 16 + lx][kb * 32 + quad * 8]);
        #pragma unroll
        for (int nt = 0; nt < 8; ++nt)
            acc[nt] = __builtin_amdgcn_mfma_f32_16x16x32_bf16(af, bfr[nt], acc[nt], 0, 0, 0);
    }
    epilogue_store<STATS>(acc, sred, sqred, biasf, m0, tid, out, stats, blockIdx.x);
}

// ---------------- FUSED gather+BN+lrelu GEMM (layers 1..5 first MLP linear) ----------------
// r8 staging structure (serial per-row, unroll-2 gather) — proven 44-VGPR/55µs operating
// point across r4/r5/r8/r9/r11 alternatives; coefs inlined from replicated raw stats.
// NOT in-place. STATS on.
__global__ __launch_bounds__(256) void gemm_gather(const u16* __restrict__ U, const int* __restrict__ row_ptr,
                                                   const int* __restrict__ col_idx, const u16* __restrict__ wp,
                                                   const float* __restrict__ biasf,
                                                   const float* __restrict__ instats,
                                                   const void* __restrict__ gammav, const void* __restrict__ betav,
                                                   size_t gelem, const int* __restrict__ mode,
                                                   u16* __restrict__ out, float* __restrict__ stats) {
    __shared__ u16 Asm[64][136];
    __shared__ float sred[4][128];
    __shared__ float sqred[4][128];
    __shared__ float coefs[256];
    const int tid = threadIdx.x;
    const int m0 = blockIdx.x * 64;
    const int rrow = tid >> 4;
    const int seg = tid & 15;

    coef_to_lds(coefs, instats, gammav, betav, gelem, *mode, tid);
    __syncthreads();

    {
        float cA[8], cB[8];
        #pragma unroll
        for (int j = 0; j < 8; ++j) {
            cA[j] = coefs[seg * 8 + j];
            cB[j] = coefs[128 + seg * 8 + j];
        }
        for (int i = 0; i < 4; ++i) {
            const int gm = m0 + i * 16 + rrow;
            float a[8];
            #pragma unroll
            for (int j = 0; j < 8; ++j) a[j] = 0.f;
            if (gm < N_NODES) {
                const uint4 v = *reinterpret_cast<const uint4*>(U + (size_t)gm * HD + seg * 8);
                const u32 w[4] = {v.x, v.y, v.z, v.w};
                #pragma unroll
                for (int p = 0; p < 4; ++p) {
                    a[2 * p]     = lrelu(cA[2 * p] * bf2f_lo(w[p]) + cB[2 * p]);
                    a[2 * p + 1] = lrelu(cA[2 * p + 1] * bf2f_hi(w[p]) + cB[2 * p + 1]);
                }
                const int s = row_ptr[gm];
                const int deg = row_ptr[gm + 1] - s;
                for (int t = 0; t < deg; t += 2) {
                    const int id0 = col_idx[s + t];
                    const bool h1 = (t + 1) < deg;
                    const int id1 = h1 ? col_idx[s + t + 1] : 0;
                    const uint4 r0 = *reinterpret_cast<const uint4*>(U + (size_t)id0 * HD + seg * 8);
                    uint4 r1; r1.x = r1.y = r1.z = r1.w = 0;
                    if (h1) r1 = *reinterpret_cast<const uint4*>(U + (size_t)id1 * HD + seg * 8);
                    const u32 w0[4] = {r0.x, r0.y, r0.z, r0.w};
                    const u32 w1[4] = {r1.x, r1.y, r1.z, r1.w};
                    #pragma unroll
                    for (int p = 0; p < 4; ++p) {
                        a[2 * p]     += lrelu(cA[2 * p] * bf2f_lo(w0[p]) + cB[2 * p]);
                        a[2 * p + 1] += lrelu(cA[2 * p + 1] * bf2f_hi(w0[p]) + cB[2 * p + 1]);
                        if (h1) {
                            a[2 * p]     += lrelu(cA[2 * p] * bf2f_lo(w1[p]) + cB[2 * p]);
                            a[2 * p + 1] += lrelu(cA[2 * p + 1] * bf2f_hi(w1[p]) + cB[2 * p + 1]);
                        }
                    }
                }
            }
            uint4 o;
            o.x = pack2(a[0], a[1]); o.y = pack2(a[2], a[3]);
            o.z = pack2(a[4], a[5]); o.w = pack2(a[6], a[7]);
            *reinterpret_cast<uint4*>(&Asm[i * 16 + rrow][seg * 8]) = o;
        }
    }
    __syncthreads();

    const int wave = tid >> 6, lane = tid & 63;
    const int quad = lane >> 4, lx = lane & 15;
    f32x4 acc[8] = {};
    #pragma unroll 2
    for (int kb = 0; kb < 4; ++kb) {
        bf16x8 bfr[8];
        #pragma unroll
        for (int nt = 0; nt < 8; ++nt)
            bfr[nt] = *reinterpret_cast<const bf16x8*>(wp + (((size_t)(kb * 8 + nt) * 64 + lane) << 3));
        const bf16x8 af = *reinterpret_cast<const bf16x8*>(&Asm[wave * 16 + lx][kb * 32 + quad * 8]);
        #pragma unroll
        for (int nt = 0; nt < 8; ++nt)
            acc[nt] = __builtin_amdgcn_mfma_f32_16x16x32_bf16(af, bfr[nt], acc[nt], 0, 0, 0);
    }
    epilogue_store<1>(acc, sred, sqred, biasf, m0, tid, out, stats, blockIdx.x);
}

// ---------------- FUSED layer-0: gather over x (C_IN cols, no BN) + GEMM ----------------
__global__ __launch_bounds__(256) void gemm_gather0(const void* __restrict__ xv, const int* __restrict__ row_ptr,
                                                    const int* __restrict__ col_idx, const u16* __restrict__ wp,
                                                    const float* __restrict__ biasf, const int* __restrict__ mode,
                                                    u16* __restrict__ out, float* __restrict__ stats) {
    __shared__ u16 Asm[64][136];
    __shared__ float sred[4][128];
    __shared__ float sqred[4][128];
    const int tid = threadIdx.x;
    const int m0 = blockIdx.x * 64;
    const int rrow = tid >> 4;
    const int seg = tid & 15;          // segs 0..5 carry data (48 cols), 6..15 zero
    const int md = *mode;
    const bool act = seg < 6;

    for (int i = 0; i < 4; ++i) {
        const int gm = m0 + i * 16 + rrow;
        float a[8];
        #pragma unroll
        for (int j = 0; j < 8; ++j) a[j] = 0.f;
        if (gm < N_NODES && act) {
            if (md) {
                const float* xf = (const float*)xv + (size_t)gm * C_IN + seg * 8;
                const float4 v0 = reinterpret_cast<const float4*>(xf)[0];
                const float4 v1 = reinterpret_cast<const float4*>(xf)[1];
                a[0] = v0.x; a[1] = v0.y; a[2] = v0.z; a[3] = v0.w;
                a[4] = v1.x; a[5] = v1.y; a[6] = v1.z; a[7] = v1.w;
            } else {
                const uint4 v = *reinterpret_cast<const uint4*>((const u16*)xv + (size_t)gm * C_IN + seg * 8);
                const u32 w[4] = {v.x, v.y, v.z, v.w};
                #pragma unroll
                for (int p = 0; p < 4; ++p) { a[2 * p] = bf2f_lo(w[p]); a[2 * p + 1] = bf2f_hi(w[p]); }
            }
        }
        if (gm < N_NODES) {
            const int s = row_ptr[gm];
            const int deg = row_ptr[gm + 1] - s;
            for (int t = 0; t < deg; t += 2) {
                const int id0 = col_idx[s + t];
                const bool h1 = (t + 1) < deg;
                const int id1 = h1 ? col_idx[s + t + 1] : 0;
                if (act) {
                    if (md) {
                        const float* p0 = (const float*)xv + (size_t)id0 * C_IN + seg * 8;
                        const float4 u0 = reinterpret_cast<const float4*>(p0)[0];
                        const float4 u1 = reinterpret_cast<const float4*>(p0)[1];
                        a[0] += u0.x; a[1] += u0.y; a[2] += u0.z; a[3] += u0.w;
                        a[4] += u1.x; a[5] += u1.y; a[6] += u1.z; a[7] += u1.w;
                        if (h1) {
                            const float* p1 = (const float*)xv + (size_t)id1 * C_IN + seg * 8;
                            const float4 t0 = reinterpret_cast<const float4*>(p1)[0];
                            const float4 t1 = reinterpret_cast<const float4*>(p1)[1];
                            a[0] += t0.x; a[1] += t0.y; a[2] += t0.z; a[3] += t0.w;
                            a[4] += t1.x; a[5] += t1.y; a[6] += t1.z; a[7] += t1.w;
                        }
                    } else {
                        const uint4 r0 = *reinterpret_cast<const uint4*>((const u16*)xv + (size_t)id0 * C_IN + seg * 8);
                        const u32 w0[4] = {r0.x, r0.y, r0.z, r0.w};
                        #pragma unroll
                        for (int p = 0; p < 4; ++p) { a[2 * p] += bf2f_lo(w0[p]); a[2 * p + 1] += bf2f_hi(w0[p]); }
                        if (h1) {
                            const uint4 r1 = *reinterpret_cast<const uint4*>((const u16*)xv + (size_t)id1 * C_IN + seg * 8);
                            const u32 w1[4] = {r1.x, r1.y, r1.z, r1.w};
                            #pragma unroll
                            for (int p = 0; p < 4; ++p) { a[2 * p] += bf2f_lo(w1[p]); a[2 * p + 1] += bf2f_hi(w1[p]); }
                        }
                    }
                }
            }
        }
        uint4 o;
        o.x = pack2(a[0], a[1]); o.y = pack2(a[2], a[3]);
        o.z = pack2(a[4], a[5]); o.w = pack2(a[6], a[7]);
        *reinterpret_cast<uint4*>(&Asm[i * 16 + rrow][seg * 8]) = o;
    }
    __syncthreads();

    const int wave = tid >> 6, lane = tid & 63;
    const int quad = lane >> 4, lx = lane & 15;
    f32x4 acc[8] = {};
    #pragma unroll 2
    for (int kb = 0; kb < 4; ++kb) {
        bf16x8 bfr[8];
        #pragma unroll
        for (int nt = 0; nt < 8; ++nt)
            bfr[nt] = *reinterpret_cast<const bf16x8*>(wp + (((size_t)(kb * 8 + nt) * 64 + lane) << 3));
        const bf16x8 af = *reinterpret_cast<const bf16x8*>(&Asm[wave * 16 + lx][kb * 32 + quad * 8]);
        #pragma unroll
        for (int nt = 0; nt < 8; ++nt)
            acc[nt] = __builtin_amdgcn_mfma_f32_16x16x32_bf16(af, bfr[nt], acc[nt], 0, 0, 0);
    }
    epilogue_store<1>(acc, sred, sqred, biasf, m0, tid, out, stats, blockIdx.x);
}

// ---------------- pooling: wave per graph, uint4 row loads, quad-parallel rows ----------------
__global__ __launch_bounds__(256) void pool_kernel(const u16* __restrict__ hf, const int* __restrict__ batch,
                                                   const int* __restrict__ mode, float* __restrict__ emb,
                                                   void* __restrict__ outv) {
    const int wave = threadIdx.x >> 6, lane = threadIdx.x & 63;
    const int g = blockIdx.x * 4 + wave;
    if (g >= N_GRAPHS) return;
    const int md = *mode;
    const int quad = lane >> 4, c = lane & 15;
    int lo = 0, hi = N_NODES;
    while (lo < hi) { int m = (lo + hi) >> 1; if (batch[m] < g) lo = m + 1; else hi = m; }
    const int s = lo;
    hi = N_NODES;
    while (lo < hi) { int m = (lo + hi) >> 1; if (batch[m] < g + 1) lo = m + 1; else hi = m; }
    const int e = lo;
    const int cnt = e - s;
    float sum[8], mx[8];
    #pragma unroll
    for (int j = 0; j < 8; ++j) { sum[j] = 0.f; mx[j] = -INFINITY; }
    for (int n = s + quad; n < e; n += 4) {
        const uint4 v = *reinterpret_cast<const uint4*>(hf + (size_t)n * HD + c * 8);
        const u32 w[4] = {v.x, v.y, v.z, v.w};
        #pragma unroll
        for (int p = 0; p < 4; ++p) {
            const float f0 = bf2f_lo(w[p]), f1 = bf2f_hi(w[p]);
            sum[2 * p] += f0; sum[2 * p + 1] += f1;
            mx[2 * p] = fmaxf(mx[2 * p], f0); mx[2 * p + 1] = fmaxf(mx[2 * p + 1], f1);
        }
    }
    #pragma unroll
    for (int j = 0; j < 8; ++j) {
        sum[j] += __shfl_xor(sum[j], 16); sum[j] += __shfl_xor(sum[j], 32);
        mx[j] = fmaxf(mx[j], __shfl_xor(mx[j], 16));
        mx[j] = fmaxf(mx[j], __shfl_xor(mx[j], 32));
    }
    if (quad == 0) {
        const float invc = 1.0f / (float)max(cnt, 1);
        const size_t base = (size_t)N_GRAPHS * 3 + (size_t)g * 256;
        #pragma unroll
        for (int j = 0; j < 8; ++j) {
            const float mean = sum[j] * invc;
            const float m2 = (cnt == 0) ? 0.f : mx[j];
            const int col = c * 8 + j;
            emb[(size_t)g * 256 + col] = mean;
            emb[(size_t)g * 256 + 128 + col] = m2;
            if (md) {
                ((float*)outv)[base + col] = mean;
                ((float*)outv)[base + 128 + col] = m2;
            } else {
                ((u16*)outv)[base + col] = f2bf(mean);
                ((u16*)outv)[base + 128 + col] = f2bf(m2);
            }
        }
    }
}

__global__ __launch_bounds__(64) void final_kernel(const float* __restrict__ emb, const void* __restrict__ fcwv,
                                                   const void* __restrict__ fcbv, const void* __restrict__ fc2wv,
                                                   const void* __restrict__ fc2bv, const int* __restrict__ mode,
                                                   void* __restrict__ outv) {
    __shared__ float es[256];
    __shared__ float hs[64];
    const int g = blockIdx.x, t = threadIdx.x;
    const int md = *mode;
    reinterpret_cast<float4*>(es)[t] = reinterpret_cast<const float4*>(emb + (size_t)g * 256)[t];
    __syncthreads();
    float acc = md ? ((const float*)fcbv)[t] : bf2f(((const u16*)fcbv)[t]);
    if (md) {
        const float* w = (const float*)fcwv;
        #pragma unroll 8
        for (int k = 0; k < 256; ++k) acc += es[k] * w[k * 64 + t];
    } else {
        const u16* w = (const u16*)fcwv;
        #pragma unroll 8
        for (int k = 0; k < 256; ++k) acc += es[k] * bf2f(w[k * 64 + t]);
    }
    hs[t] = lrelu(acc);
    __syncthreads();
    if (t < 3) {
        float o = md ? ((const float*)fc2bv)[t] : bf2f(((const u16*)fc2bv)[t]);
        if (md) {
            const float* w = (const float*)fc2wv;
            #pragma unroll 8
            for (int j = 0; j < 64; ++j) o += hs[j] * w[j * 3 + t];
            ((float*)outv)[(size_t)g * 3 + t] = o;
        } else {
            const u16* w = (const u16*)fc2wv;
            #pragma unroll 8
            for (int j = 0; j < 64; ++j) o += hs[j] * bf2f(w[j * 3 + t]);
            ((u16*)outv)[(size_t)g * 3 + t] = f2bf(o);
        }
    }
}

// ---------------- launch ----------------
static inline size_t align256(size_t x) { return (x + 255) & ~(size_t)255; }

extern "C" void kernel_launch(void* const* d_in, const int* in_sizes, int n_in,
                              void* d_out, int out_size, void* d_ws, size_t ws_size,
                              hipStream_t stream) {
    (void)in_sizes; (void)n_in; (void)out_size; (void)ws_size;
    const void* x    = d_in[0];
    const void* W1a  = d_in[2];
    const void* W1b  = d_in[3];
    const void* b1   = d_in[4];
    const void* g1   = d_in[5];
    const void* be1  = d_in[6];
    const void* W2   = d_in[7];
    const void* b2   = d_in[8];
    const void* gn   = d_in[9];
    const void* bnb  = d_in[10];
    const void* fcw  = d_in[11];
    const void* fcb  = d_in[12];
    const void* fc2w = d_in[13];
    const void* fc2b = d_in[14];
    const int* ei    = (const int*)d_in[15];
    const int* batch = (const int*)d_in[16];

    char* p = (char*)d_ws;
    size_t off = 0;
    u16* zb = (u16*)(p + off); off += align256((size_t)N_NODES * HD * 2);
    u16* hb = (u16*)(p + off); off += align256((size_t)N_NODES * HD * 2);
    u16* wpack = (u16*)(p + off); off += align256((size_t)12 * HD * HD * 2);
    float* biasf = (float*)(p + off); off += align256((size_t)12 * HD * 4);
    float* emb = (float*)(p + off); off += align256((size_t)N_GRAPHS * 256 * 4);
    int* row_ptr = (int*)(p + off); off += align256((size_t)(N_NODES + 1) * 4);
    int* cursor = (int*)(p + off); off += align256((size_t)N_NODES * 4);
    int* col_idx = (int*)(p + off); off += align256((size_t)N_EDGES * 4);
    int* bsum = (int*)(p + off); off += align256((size_t)SB * 4);
    float* statsAll = (float*)(p + off); off += align256((size_t)12 * NREP * 256 * 4);
    int* mode = (int*)(p + off); off += align256(4);

    const int EB = (N_EDGES + 255) / 256;
    const int GBM = (N_NODES + 63) / 64;     // 1563

    detect_kernel<<<1, 256, 0, stream>>>((const u16*)x, mode);

    hipMemsetAsync(cursor, 0, (size_t)N_NODES * 4, stream);
    hipMemsetAsync(statsAll, 0, (size_t)12 * NREP * 256 * 4, stream);
    hist_kernel<<<EB, 256, 0, stream>>>(ei + N_EDGES, cursor);
    scan1_kernel<<<SB, 256, 0, stream>>>(cursor, bsum);
    scan2_kernel<<<1, 512, 0, stream>>>(bsum, row_ptr);
    scan3_kernel<<<SB, 256, 0, stream>>>(cursor, bsum, row_ptr);
    hipMemcpyAsync(cursor, row_ptr, (size_t)N_NODES * 4, hipMemcpyDeviceToDevice, stream);
    fill_kernel<<<EB, 256, 0, stream>>>(ei, ei + N_EDGES, cursor, col_idx);
    pack_w_kernel<<<96, 256, 0, stream>>>(W1a, W1b, W2, mode, wpack);
    pack_b_kernel<<<6, 256, 0, stream>>>(b1, b2, mode, biasf);

    u16* cur = zb;
    u16* oth = hb;
    for (int l = 0; l < NLAYERS; ++l) {
        float* statsA = statsAll + (size_t)l * NREP * 256;
        float* statsB = statsAll + (size_t)(6 + l) * NREP * 256;
        float* statsBprev = statsAll + (size_t)(6 + l - 1) * NREP * 256;
        if (l == 0) {
            // fused gather(x) + gemm1 (no BN on input): x -> cur
            gemm_gather0<<<GBM, 256, 0, stream>>>(x, row_ptr, col_idx, wpack,
                                                  biasf, mode, cur, statsA);
        } else {
            // fused gather+BN(outer,l-1)+lrelu + gemm1: cur -> oth (not in-place)
            gemm_gather<<<GBM, 256, 0, stream>>>(cur, row_ptr, col_idx,
                                                 wpack + (size_t)l * HD * HD,
                                                 biasf + (size_t)l * HD, statsBprev, gn, bnb,
                                                 (size_t)(l - 1) * HD, mode, oth, statsA);
            u16* t = cur; cur = oth; oth = t;
        }
        if (l < NLAYERS - 1) {
            gemm_mfma<1, 1><<<GBM, 256, 0, stream>>>(cur, wpack + (size_t)(6 + l) * HD * HD,
                                                     biasf + (size_t)(6 + l) * HD, statsA, g1, be1,
                                                     (size_t)l * HD, mode, cur, statsB);
        } else {
            gemm_mfma<1, 0><<<GBM, 256, 0, stream>>>(cur, wpack + (size_t)(6 + l) * HD * HD,
                                                     biasf + (size_t)(6 + l) * HD, statsA, g1, be1,
                                                     (size_t)l * HD, mode, cur, nullptr);
        }
    }

    pool_kernel<<<(N_GRAPHS + 3) / 4, 256, 0, stream>>>(cur, batch, mode, emb, d_out);
    final_kernel<<<N_GRAPHS, 64, 0, stream>>>(emb, fcw, fcb, fc2w, fc2b, mode, d_out);
}

// Round 13
// 624.558 us; speedup vs baseline: 3.1326x; 1.0889x over previous
//
#include <hip/hip_runtime.h>
#include <stdint.h>

#define N_NODES 100000
#define N_EDGES 400000
#define N_GRAPHS 2000
#define C_IN 48
#define HD 128
#define NLAYERS 6
#define BN_EPS 1e-5f
#define NSLOPE 0.01f
#define SB 391   // ceil(N_NODES/256)
#define NREP 8   // stats replication factor

typedef uint16_t u16;
typedef uint32_t u32;
typedef short bf16x8 __attribute__((ext_vector_type(8)));
typedef float f32x4 __attribute__((ext_vector_type(4)));

__device__ __forceinline__ float bf2f_lo(u32 v) { return __uint_as_float(v << 16); }
__device__ __forceinline__ float bf2f_hi(u32 v) { return __uint_as_float(v & 0xffff0000u); }
__device__ __forceinline__ float bf2f(u16 h) { return __uint_as_float(((u32)h) << 16); }
__device__ __forceinline__ u16 f2bf(float f) {
    u32 u = __float_as_uint(f);
    u32 r = (u + 0x7fffu + ((u >> 16) & 1u)) >> 16;
    return (u16)r;
}
__device__ __forceinline__ u32 pack2(float a, float b) {
    return (u32)f2bf(a) | ((u32)f2bf(b) << 16);
}
__device__ __forceinline__ float lrelu(float v) { return v >= 0.f ? v : v * NSLOPE; }

// dtype detection: mode=1 -> float inputs are fp32; mode=0 -> bf16.
__global__ __launch_bounds__(256) void detect_kernel(const u16* __restrict__ x, int* __restrict__ mode) {
    __shared__ int flag;
    if (threadIdx.x == 0) flag = 0;
    __syncthreads();
    int local = 0;
    for (int i = threadIdx.x; i < 16384; i += 256) {
        float a = fabsf(bf2f(x[i]));
        if (!(a < 1e4f)) local = 1;
    }
    if (local) flag = 1;
    __syncthreads();
    if (threadIdx.x == 0) mode[0] = flag;
}

// ---------------- CSR build ----------------
__global__ __launch_bounds__(256) void hist_kernel(const int* __restrict__ dst, int* __restrict__ cnt) {
    int e = blockIdx.x * 256 + threadIdx.x;
    if (e < N_EDGES) atomicAdd(&cnt[dst[e]], 1);
}

__global__ __launch_bounds__(256) void scan1_kernel(const int* __restrict__ cnt, int* __restrict__ bsum) {
    __shared__ int s[256];
    const int t = threadIdx.x;
    const int i = blockIdx.x * 256 + t;
    s[t] = (i < N_NODES) ? cnt[i] : 0;
    __syncthreads();
    for (int d = 128; d > 0; d >>= 1) {
        if (t < d) s[t] += s[t + d];
        __syncthreads();
    }
    if (t == 0) bsum[blockIdx.x] = s[0];
}

__global__ __launch_bounds__(512) void scan2_kernel(int* __restrict__ bsum, int* __restrict__ row_ptr) {
    __shared__ int s[SB];
    const int t = threadIdx.x;
    if (t < SB) s[t] = bsum[t];
    __syncthreads();
    if (t == 0) {
        int run = 0;
        for (int b = 0; b < SB; ++b) { int v = s[b]; s[b] = run; run += v; }
        row_ptr[0] = 0;
    }
    __syncthreads();
    if (t < SB) bsum[t] = s[t];
}

__global__ __launch_bounds__(256) void scan3_kernel(const int* __restrict__ cnt, const int* __restrict__ bsum,
                                                    int* __restrict__ row_ptr) {
    __shared__ int s[256];
    const int t = threadIdx.x;
    const int i = blockIdx.x * 256 + t;
    s[t] = (i < N_NODES) ? cnt[i] : 0;
    __syncthreads();
    if (t == 0) {
        int run = bsum[blockIdx.x];
        for (int j = 0; j < 256; ++j) { run += s[j]; s[j] = run; }
    }
    __syncthreads();
    if (i < N_NODES) row_ptr[i + 1] = s[t];
}

__global__ __launch_bounds__(256) void fill_kernel(const int* __restrict__ src, const int* __restrict__ dst,
                                                   int* __restrict__ cursor, int* __restrict__ col_idx) {
    int e = blockIdx.x * 256 + threadIdx.x;
    if (e < N_EDGES) {
        int d = dst[e];
        int slot = atomicAdd(&cursor[d], 1);
        col_idx[slot] = src[e];
    }
}

// ---------------- weight pre-pack into MFMA B-fragment layout (bf16) ----------------
__global__ __launch_bounds__(256) void pack_w_kernel(const void* __restrict__ W1a, const void* __restrict__ W1b,
                                                     const void* __restrict__ W2, const int* __restrict__ mode,
                                                     u16* __restrict__ wpack) {
    const int t = blockIdx.x * 256 + threadIdx.x;  // 12*2048 = 24576
    if (t >= 24576) return;
    const int mat = t >> 11;
    const int r = t & 2047;
    const int l = r & 63;
    const int f = r >> 6;
    const int kb = f >> 3, nt = f & 7;
    const int k0 = kb * 32 + (l >> 4) * 8;
    const int n = nt * 16 + (l & 15);
    const int md = *mode;
    u16 vals[8];
    #pragma unroll
    for (int j = 0; j < 8; ++j) {
        const int k = k0 + j;
        float v;
        if (mat == 0) {
            v = (k < C_IN) ? (md ? ((const float*)W1a)[k * HD + n] : bf2f(((const u16*)W1a)[k * HD + n])) : 0.f;
        } else if (mat < 6) {
            const size_t o = (size_t)(mat - 1) * HD * HD + (size_t)k * HD + n;
            v = md ? ((const float*)W1b)[o] : bf2f(((const u16*)W1b)[o]);
        } else {
            const size_t o = (size_t)(mat - 6) * HD * HD + (size_t)k * HD + n;
            v = md ? ((const float*)W2)[o] : bf2f(((const u16*)W2)[o]);
        }
        vals[j] = f2bf(v);
    }
    uint4 o;
    o.x = (u32)vals[0] | ((u32)vals[1] << 16);
    o.y = (u32)vals[2] | ((u32)vals[3] << 16);
    o.z = (u32)vals[4] | ((u32)vals[5] << 16);
    o.w = (u32)vals[6] | ((u32)vals[7] << 16);
    *reinterpret_cast<uint4*>(wpack + (size_t)t * 8) = o;
}

// ---------------- bias pre-pack to f32 ----------------
__global__ __launch_bounds__(256) void pack_b_kernel(const void* __restrict__ b1, const void* __restrict__ b2,
                                                     const int* __restrict__ mode, float* __restrict__ biasf) {
    const int i = blockIdx.x * 256 + threadIdx.x;  // 12*128
    if (i >= 12 * HD) return;
    const int mat = i >> 7, c = i & 127;
    const int md = *mode;
    float v;
    if (mat < 6) v = md ? ((const float*)b1)[mat * HD + c] : bf2f(((const u16*)b1)[mat * HD + c]);
    else         v = md ? ((const float*)b2)[(mat - 6) * HD + c] : bf2f(((const u16*)b2)[(mat - 6) * HD + c]);
    biasf[i] = v;
}

// ---- shared helper: compute BN coef[256]={A,B} in LDS from replicated raw stats ----
__device__ __forceinline__ void coef_to_lds(float* coefs, const float* __restrict__ instats,
                                            const void* __restrict__ gammav, const void* __restrict__ betav,
                                            size_t gelem, int md, int tid) {
    if (tid < 128) {
        float sm = 0.f, sq = 0.f;
        #pragma unroll
        for (int rep = 0; rep < NREP; ++rep) {
            sm += instats[rep * 256 + tid];
            sq += instats[rep * 256 + 128 + tid];
        }
        const float inv_n = 1.0f / (float)N_NODES;
        const float mean = sm * inv_n;
        const float var = fmaxf(sq * inv_n - mean * mean, 0.f);
        const float rs = rsqrtf(var + BN_EPS);
        const float g  = md ? ((const float*)gammav)[gelem + tid] : bf2f(((const u16*)gammav)[gelem + tid]);
        const float be = md ? ((const float*)betav)[gelem + tid]  : bf2f(((const u16*)betav)[gelem + tid]);
        const float A = g * rs;
        coefs[tid] = A;
        coefs[128 + tid] = be - A * mean;
    }
}

// ---- shared epilogue for BM=64 kernels ----
template <int STATS>
__device__ __forceinline__ void epilogue_store(f32x4* acc, float (*sred)[128], float (*sqred)[128],
                                               const float* __restrict__ biasf, int m0, int tid,
                                               u16* out, float* __restrict__ stats, int blkid) {
    const int wave = tid >> 6, lane = tid & 63;
    const int quad = lane >> 4, lx = lane & 15;
    const int mrow0 = m0 + wave * 16;
    #pragma unroll
    for (int nt = 0; nt < 8; ++nt) {
        const int n = nt * 16 + lx;
        const float bj = biasf[n];
        float s = 0.f, q = 0.f;
        #pragma unroll
        for (int r = 0; r < 4; ++r) {
            const int m = mrow0 + quad * 4 + r;
            if (m < N_NODES) {
                const float v = acc[nt][r] + bj;
                out[(size_t)m * HD + n] = f2bf(v);
                if (STATS) { s += v; q += v * v; }
            }
        }
        if (STATS) {
            s += __shfl_xor(s, 16); s += __shfl_xor(s, 32);
            q += __shfl_xor(q, 16); q += __shfl_xor(q, 32);
            if (quad == 0) { sred[wave][n] = s; sqred[wave][n] = q; }
        }
    }
    if (STATS) {
        __syncthreads();
        float* sdst = stats + (size_t)(blkid & (NREP - 1)) * 256;
        if (tid < 128) {
            atomicAdd(&sdst[tid], sred[0][tid] + sred[1][tid] + sred[2][tid] + sred[3][tid]);
        } else if (tid < 256) {
            const int c2 = tid - 128;
            atomicAdd(&sdst[128 + c2], sqred[0][c2] + sqred[1][c2] + sqred[2][c2] + sqred[3][c2]);
        }
    }
}

// ---------------- plain MFMA GEMM: BM=64, LDS A-stage, direct-store epilogue ----------------
// TRANS: BN coefs computed in-block (replicated raw instats + gamma/beta), applied while staging.
// IN-PLACE SAFE (out == A): block reads only its own rows.
template <int TRANS, int STATS>
__global__ __launch_bounds__(256) void gemm_mfma(const u16* A, const u16* __restrict__ wp,
                                                 const float* __restrict__ biasf,
                                                 const float* __restrict__ instats,
                                                 const void* __restrict__ gammav, const void* __restrict__ betav,
                                                 size_t gelem, const int* __restrict__ mode,
                                                 u16* out, float* __restrict__ stats) {
    __shared__ u16 Asm[64][136];
    __shared__ float sred[4][128];
    __shared__ float sqred[4][128];
    __shared__ float coefs[256];
    const int tid = threadIdx.x;
    const int m0 = blockIdx.x * 64;
    const int rrow = tid >> 4;   // 0..15
    const int seg = tid & 15;    // cols seg*8..seg*8+7

    if (TRANS) {
        coef_to_lds(coefs, instats, gammav, betav, gelem, *mode, tid);
        __syncthreads();
    }

    {
        float cA[8], cB[8];
        if (TRANS) {
            #pragma unroll
            for (int j = 0; j < 8; ++j) {
                cA[j] = coefs[seg * 8 + j];
                cB[j] = coefs[128 + seg * 8 + j];
            }
        }
        uint4 v[4];
        #pragma unroll
        for (int i = 0; i < 4; ++i) {
            const int gm = m0 + i * 16 + rrow;
            if (gm < N_NODES) v[i] = *reinterpret_cast<const uint4*>(A + (size_t)gm * HD + seg * 8);
            else { v[i].x = 0; v[i].y = 0; v[i].z = 0; v[i].w = 0; }
        }
        #pragma unroll
        for (int i = 0; i < 4; ++i) {
            uint4 o = v[i];
            if (TRANS) {
                u32 w[4] = {o.x, o.y, o.z, o.w};
                #pragma unroll
                for (int p = 0; p < 4; ++p) {
                    const float lo = lrelu(cA[2 * p] * bf2f_lo(w[p]) + cB[2 * p]);
                    const float hi = lrelu(cA[2 * p + 1] * bf2f_hi(w[p]) + cB[2 * p + 1]);
                    w[p] = pack2(lo, hi);
                }
                o.x = w[0]; o.y = w[1]; o.z = w[2]; o.w = w[3];
            }
            *reinterpret_cast<uint4*>(&Asm[i * 16 + rrow][seg * 8]) = o;
        }
    }
    __syncthreads();

    const int wave = tid >> 6, lane = tid & 63;
    const int quad = lane >> 4, lx = lane & 15;
    f32x4 acc[8] = {};
    #pragma unroll 2
    for (int kb = 0; kb < 4; ++kb) {
        bf16x8 bfr[8];
        #pragma unroll
        for (int nt = 0; nt < 8; ++nt)
            bfr[nt] = *reinterpret_cast<const bf16x8*>(wp + (((size_t)(kb * 8 + nt) * 64 + lane) << 3));
        const bf16x8 af = *reinterpret_cast<const bf16x8*>(&Asm[wave * 16 + lx][kb * 32 + quad * 8]);
        #pragma unroll
        for (int nt = 0; nt < 8; ++nt)
            acc[nt] = __builtin_amdgcn_mfma_f32_16x16x32_bf16(af, bfr[nt], acc[nt], 0, 0, 0);
    }
    epilogue_store<STATS>(acc, sred, sqred, biasf, m0, tid, out, stats, blockIdx.x);
}

// ---------------- FUSED gather+BN+lrelu GEMM — BM=32 for 2x grid TLP ----------------
// 3125 blocks (12.2/CU) vs 1563: more resident waves to hide random-gather latency;
// per-thread serial chain halves (2 rows). Wave w: rows (w&1)*16..+16, cols (w>>1)*64..+64.
// NOT in-place. STATS on.
__global__ __launch_bounds__(256) void gemm_gather(const u16* __restrict__ U, const int* __restrict__ row_ptr,
                                                   const int* __restrict__ col_idx, const u16* __restrict__ wp,
                                                   const float* __restrict__ biasf,
                                                   const float* __restrict__ instats,
                                                   const void* __restrict__ gammav, const void* __restrict__ betav,
                                                   size_t gelem, const int* __restrict__ mode,
                                                   u16* __restrict__ out, float* __restrict__ stats) {
    __shared__ u16 Asm[32][136];
    __shared__ float sred[2][128];
    __shared__ float sqred[2][128];
    __shared__ float coefs[256];
    const int tid = threadIdx.x;
    const int m0 = blockIdx.x * 32;
    const int rrow = tid >> 4;   // 0..15
    const int seg = tid & 15;

    coef_to_lds(coefs, instats, gammav, betav, gelem, *mode, tid);
    __syncthreads();

    {
        float cA[8], cB[8];
        #pragma unroll
        for (int j = 0; j < 8; ++j) {
            cA[j] = coefs[seg * 8 + j];
            cB[j] = coefs[128 + seg * 8 + j];
        }
        for (int i = 0; i < 2; ++i) {
            const int gm = m0 + i * 16 + rrow;
            float a[8];
            #pragma unroll
            for (int j = 0; j < 8; ++j) a[j] = 0.f;
            if (gm < N_NODES) {
                const uint4 v = *reinterpret_cast<const uint4*>(U + (size_t)gm * HD + seg * 8);
                const u32 w[4] = {v.x, v.y, v.z, v.w};
                #pragma unroll
                for (int p = 0; p < 4; ++p) {
                    a[2 * p]     = lrelu(cA[2 * p] * bf2f_lo(w[p]) + cB[2 * p]);
                    a[2 * p + 1] = lrelu(cA[2 * p + 1] * bf2f_hi(w[p]) + cB[2 * p + 1]);
                }
                const int s = row_ptr[gm];
                const int deg = row_ptr[gm + 1] - s;
                for (int t = 0; t < deg; t += 2) {
                    const int id0 = col_idx[s + t];
                    const bool h1 = (t + 1) < deg;
                    const int id1 = h1 ? col_idx[s + t + 1] : 0;
                    const uint4 r0 = *reinterpret_cast<const uint4*>(U + (size_t)id0 * HD + seg * 8);
                    uint4 r1; r1.x = r1.y = r1.z = r1.w = 0;
                    if (h1) r1 = *reinterpret_cast<const uint4*>(U + (size_t)id1 * HD + seg * 8);
                    const u32 w0[4] = {r0.x, r0.y, r0.z, r0.w};
                    const u32 w1[4] = {r1.x, r1.y, r1.z, r1.w};
                    #pragma unroll
                    for (int p = 0; p < 4; ++p) {
                        a[2 * p]     += lrelu(cA[2 * p] * bf2f_lo(w0[p]) + cB[2 * p]);
                        a[2 * p + 1] += lrelu(cA[2 * p + 1] * bf2f_hi(w0[p]) + cB[2 * p + 1]);
                        if (h1) {
                            a[2 * p]     += lrelu(cA[2 * p] * bf2f_lo(w1[p]) + cB[2 * p]);
                            a[2 * p + 1] += lrelu(cA[2 * p + 1] * bf2f_hi(w1[p]) + cB[2 * p + 1]);
                        }
                    }
                }
            }
            uint4 o;
            o.x = pack2(a[0], a[1]); o.y = pack2(a[2], a[3]);
            o.z = pack2(a[4], a[5]); o.w = pack2(a[6], a[7]);
            *reinterpret_cast<uint4*>(&Asm[i * 16 + rrow][seg * 8]) = o;
        }
    }
    __syncthreads();

    const int wave = tid >> 6, lane = tid & 63;
    const int quad = lane >> 4, lx = lane & 15;
    const int rowhalf = wave & 1;     // rows rowhalf*16 .. +16
    const int colhalf = wave >> 1;    // cols colhalf*64 .. +64
    const int wrow = rowhalf * 16;
    f32x4 acc[4] = {};
    #pragma unroll
    for (int kb = 0; kb < 4; ++kb) {
        bf16x8 bfr[4];
        #pragma unroll
        for (int nt = 0; nt < 4; ++nt)
            bfr[nt] = *reinterpret_cast<const bf16x8*>(wp + (((size_t)(kb * 8 + colhalf * 4 + nt) * 64 + lane) << 3));
        const bf16x8 af = *reinterpret_cast<const bf16x8*>(&Asm[wrow + lx][kb * 32 + quad * 8]);
        #pragma unroll
        for (int nt = 0; nt < 4; ++nt)
            acc[nt] = __builtin_amdgcn_mfma_f32_16x16x32_bf16(af, bfr[nt], acc[nt], 0, 0, 0);
    }

    // epilogue: bias + store + stats (wave covers 16 rows x 64 cols)
    const int mrow0 = m0 + wrow;
    #pragma unroll
    for (int nt = 0; nt < 4; ++nt) {
        const int n = colhalf * 64 + nt * 16 + lx;
        const float bj = biasf[n];
        float s = 0.f, q = 0.f;
        #pragma unroll
        for (int r = 0; r < 4; ++r) {
            const int m = mrow0 + quad * 4 + r;
            if (m < N_NODES) {
                const float v = acc[nt][r] + bj;
                out[(size_t)m * HD + n] = f2bf(v);
                s += v; q += v * v;
            }
        }
        s += __shfl_xor(s, 16); s += __shfl_xor(s, 32);
        q += __shfl_xor(q, 16); q += __shfl_xor(q, 32);
        if (quad == 0) { sred[rowhalf][n] = s; sqred[rowhalf][n] = q; }
    }
    __syncthreads();
    float* sdst = stats + (size_t)(blockIdx.x & (NREP - 1)) * 256;
    if (tid < 128) {
        atomicAdd(&sdst[tid], sred[0][tid] + sred[1][tid]);
    } else if (tid < 256) {
        const int c2 = tid - 128;
        atomicAdd(&sdst[128 + c2], sqred[0][c2] + sqred[1][c2]);
    }
}

// ---------------- FUSED layer-0: gather over x (C_IN cols, no BN) + GEMM — BM=32 ----------------
__global__ __launch_bounds__(256) void gemm_gather0(const void* __restrict__ xv, const int* __restrict__ row_ptr,
                                                    const int* __restrict__ col_idx, const u16* __restrict__ wp,
                                                    const float* __restrict__ biasf, const int* __restrict__ mode,
                                                    u16* __restrict__ out, float* __restrict__ stats) {
    __shared__ u16 Asm[32][136];
    __shared__ float sred[2][128];
    __shared__ float sqred[2][128];
    const int tid = threadIdx.x;
    const int m0 = blockIdx.x * 32;
    const int rrow = tid >> 4;
    const int seg = tid & 15;          // segs 0..5 carry data (48 cols), 6..15 zero
    const int md = *mode;
    const bool act = seg < 6;

    for (int i = 0; i < 2; ++i) {
        const int gm = m0 + i * 16 + rrow;
        float a[8];
        #pragma unroll
        for (int j = 0; j < 8; ++j) a[j] = 0.f;
        if (gm < N_NODES && act) {
            if (md) {
                const float* xf = (const float*)xv + (size_t)gm * C_IN + seg * 8;
                const float4 v0 = reinterpret_cast<const float4*>(xf)[0];
                const float4 v1 = reinterpret_cast<const float4*>(xf)[1];
                a[0] = v0.x; a[1] = v0.y; a[2] = v0.z; a[3] = v0.w;
                a[4] = v1.x; a[5] = v1.y; a[6] = v1.z; a[7] = v1.w;
            } else {
                const uint4 v = *reinterpret_cast<const uint4*>((const u16*)xv + (size_t)gm * C_IN + seg * 8);
                const u32 w[4] = {v.x, v.y, v.z, v.w};
                #pragma unroll
                for (int p = 0; p < 4; ++p) { a[2 * p] = bf2f_lo(w[p]); a[2 * p + 1] = bf2f_hi(w[p]); }
            }
        }
        if (gm < N_NODES) {
            const int s = row_ptr[gm];
            const int deg = row_ptr[gm + 1] - s;
            for (int t = 0; t < deg; t += 2) {
                const int id0 = col_idx[s + t];
                const bool h1 = (t + 1) < deg;
                const int id1 = h1 ? col_idx[s + t + 1] : 0;
                if (act) {
                    if (md) {
                        const float* p0 = (const float*)xv + (size_t)id0 * C_IN + seg * 8;
                        const float4 u0 = reinterpret_cast<const float4*>(p0)[0];
                        const float4 u1 = reinterpret_cast<const float4*>(p0)[1];
                        a[0] += u0.x; a[1] += u0.y; a[2] += u0.z; a[3] += u0.w;
                        a[4] += u1.x; a[5] += u1.y; a[6] += u1.z; a[7] += u1.w;
                        if (h1) {
                            const float* p1 = (const float*)xv + (size_t)id1 * C_IN + seg * 8;
                            const float4 t0 = reinterpret_cast<const float4*>(p1)[0];
                            const float4 t1 = reinterpret_cast<const float4*>(p1)[1];
                            a[0] += t0.x; a[1] += t0.y; a[2] += t0.z; a[3] += t0.w;
                            a[4] += t1.x; a[5] += t1.y; a[6] += t1.z; a[7] += t1.w;
                        }
                    } else {
                        const uint4 r0 = *reinterpret_cast<const uint4*>((const u16*)xv + (size_t)id0 * C_IN + seg * 8);
                        const u32 w0[4] = {r0.x, r0.y, r0.z, r0.w};
                        #pragma unroll
                        for (int p = 0; p < 4; ++p) { a[2 * p] += bf2f_lo(w0[p]); a[2 * p + 1] += bf2f_hi(w0[p]); }
                        if (h1) {
                            const uint4 r1 = *reinterpret_cast<const uint4*>((const u16*)xv + (size_t)id1 * C_IN + seg * 8);
                            const u32 w1[4] = {r1.x, r1.y, r1.z, r1.w};
                            #pragma unroll
                            for (int p = 0; p < 4; ++p) { a[2 * p] += bf2f_lo(w1[p]); a[2 * p + 1] += bf2f_hi(w1[p]); }
                        }
                    }
                }
            }
        }
        uint4 o;
        o.x = pack2(a[0], a[1]); o.y = pack2(a[2], a[3]);
        o.z = pack2(a[4], a[5]); o.w = pack2(a[6], a[7]);
        *reinterpret_cast<uint4*>(&Asm[i * 16 + rrow][seg * 8]) = o;
    }
    __syncthreads();

    const int wave = tid >> 6, lane = tid & 63;
    const int quad = lane >> 4, lx = lane & 15;
    const int rowhalf = wave & 1;
    const int colhalf = wave >> 1;
    const int wrow = rowhalf * 16;
    f32x4 acc[4] = {};
    #pragma unroll
    for (int kb = 0; kb < 4; ++kb) {
        bf16x8 bfr[4];
        #pragma unroll
        for (int nt = 0; nt < 4; ++nt)
            bfr[nt] = *reinterpret_cast<const bf16x8*>(wp + (((size_t)(kb * 8 + colhalf * 4 + nt) * 64 + lane) << 3));
        const bf16x8 af = *reinterpret_cast<const bf16x8*>(&Asm[wrow + lx][kb * 32 + quad * 8]);
        #pragma unroll
        for (int nt = 0; nt < 4; ++nt)
            acc[nt] = __builtin_amdgcn_mfma_f32_16x16x32_bf16(af, bfr[nt], acc[nt], 0, 0, 0);
    }

    const int mrow0 = m0 + wrow;
    #pragma unroll
    for (int nt = 0; nt < 4; ++nt) {
        const int n = colhalf * 64 + nt * 16 + lx;
        const float bj = biasf[n];
        float s = 0.f, q = 0.f;
        #pragma unroll
        for (int r = 0; r < 4; ++r) {
            const int m = mrow0 + quad * 4 + r;
            if (m < N_NODES) {
                const float v = acc[nt][r] + bj;
                out[(size_t)m * HD + n] = f2bf(v);
                s += v; q += v * v;
            }
        }
        s += __shfl_xor(s, 16); s += __shfl_xor(s, 32);
        q += __shfl_xor(q, 16); q += __shfl_xor(q, 32);
        if (quad == 0) { sred[rowhalf][n] = s; sqred[rowhalf][n] = q; }
    }
    __syncthreads();
    float* sdst = stats + (size_t)(blockIdx.x & (NREP - 1)) * 256;
    if (tid < 128) {
        atomicAdd(&sdst[tid], sred[0][tid] + sred[1][tid]);
    } else if (tid < 256) {
        const int c2 = tid - 128;
        atomicAdd(&sdst[128 + c2], sqred[0][c2] + sqred[1][c2]);
    }
}

// ---------------- pooling: wave per graph, uint4 row loads, quad-parallel rows ----------------
__global__ __launch_bounds__(256) void pool_kernel(const u16* __restrict__ hf, const int* __restrict__ batch,
                                                   const int* __restrict__ mode, float* __restrict__ emb,
                                                   void* __restrict__ outv) {
    const int wave = threadIdx.x >> 6, lane = threadIdx.x & 63;
    const int g = blockIdx.x * 4 + wave;
    if (g >= N_GRAPHS) return;
    const int md = *mode;
    const int quad = lane >> 4, c = lane & 15;
    int lo = 0, hi = N_NODES;
    while (lo < hi) { int m = (lo + hi) >> 1; if (batch[m] < g) lo = m + 1; else hi = m; }
    const int s = lo;
    hi = N_NODES;
    while (lo < hi) { int m = (lo + hi) >> 1; if (batch[m] < g + 1) lo = m + 1; else hi = m; }
    const int e = lo;
    const int cnt = e - s;
    float sum[8], mx[8];
    #pragma unroll
    for (int j = 0; j < 8; ++j) { sum[j] = 0.f; mx[j] = -INFINITY; }
    for (int n = s + quad; n < e; n += 4) {
        const uint4 v = *reinterpret_cast<const uint4*>(hf + (size_t)n * HD + c * 8);
        const u32 w[4] = {v.x, v.y, v.z, v.w};
        #pragma unroll
        for (int p = 0; p < 4; ++p) {
            const float f0 = bf2f_lo(w[p]), f1 = bf2f_hi(w[p]);
            sum[2 * p] += f0; sum[2 * p + 1] += f1;
            mx[2 * p] = fmaxf(mx[2 * p], f0); mx[2 * p + 1] = fmaxf(mx[2 * p + 1], f1);
        }
    }
    #pragma unroll
    for (int j = 0; j < 8; ++j) {
        sum[j] += __shfl_xor(sum[j], 16); sum[j] += __shfl_xor(sum[j], 32);
        mx[j] = fmaxf(mx[j], __shfl_xor(mx[j], 16));
        mx[j] = fmaxf(mx[j], __shfl_xor(mx[j], 32));
    }
    if (quad == 0) {
        const float invc = 1.0f / (float)max(cnt, 1);
        const size_t base = (size_t)N_GRAPHS * 3 + (size_t)g * 256;
        #pragma unroll
        for (int j = 0; j < 8; ++j) {
            const float mean = sum[j] * invc;
            const float m2 = (cnt == 0) ? 0.f : mx[j];
            const int col = c * 8 + j;
            emb[(size_t)g * 256 + col] = mean;
            emb[(size_t)g * 256 + 128 + col] = m2;
            if (md) {
                ((float*)outv)[base + col] = mean;
                ((float*)outv)[base + 128 + col] = m2;
            } else {
                ((u16*)outv)[base + col] = f2bf(mean);
                ((u16*)outv)[base + 128 + col] = f2bf(m2);
            }
        }
    }
}

__global__ __launch_bounds__(64) void final_kernel(const float* __restrict__ emb, const void* __restrict__ fcwv,
                                                   const void* __restrict__ fcbv, const void* __restrict__ fc2wv,
                                                   const void* __restrict__ fc2bv, const int* __restrict__ mode,
                                                   void* __restrict__ outv) {
    __shared__ float es[256];
    __shared__ float hs[64];
    const int g = blockIdx.x, t = threadIdx.x;
    const int md = *mode;
    reinterpret_cast<float4*>(es)[t] = reinterpret_cast<const float4*>(emb + (size_t)g * 256)[t];
    __syncthreads();
    float acc = md ? ((const float*)fcbv)[t] : bf2f(((const u16*)fcbv)[t]);
    if (md) {
        const float* w = (const float*)fcwv;
        #pragma unroll 8
        for (int k = 0; k < 256; ++k) acc += es[k] * w[k * 64 + t];
    } else {
        const u16* w = (const u16*)fcwv;
        #pragma unroll 8
        for (int k = 0; k < 256; ++k) acc += es[k] * bf2f(w[k * 64 + t]);
    }
    hs[t] = lrelu(acc);
    __syncthreads();
    if (t < 3) {
        float o = md ? ((const float*)fc2bv)[t] : bf2f(((const u16*)fc2bv)[t]);
        if (md) {
            const float* w = (const float*)fc2wv;
            #pragma unroll 8
            for (int j = 0; j < 64; ++j) o += hs[j] * w[j * 3 + t];
            ((float*)outv)[(size_t)g * 3 + t] = o;
        } else {
            const u16* w = (const u16*)fc2wv;
            #pragma unroll 8
            for (int j = 0; j < 64; ++j) o += hs[j] * bf2f(w[j * 3 + t]);
            ((u16*)outv)[(size_t)g * 3 + t] = f2bf(o);
        }
    }
}

// ---------------- launch ----------------
static inline size_t align256(size_t x) { return (x + 255) & ~(size_t)255; }

extern "C" void kernel_launch(void* const* d_in, const int* in_sizes, int n_in,
                              void* d_out, int out_size, void* d_ws, size_t ws_size,
                              hipStream_t stream) {
    (void)in_sizes; (void)n_in; (void)out_size; (void)ws_size;
    const void* x    = d_in[0];
    const void* W1a  = d_in[2];
    const void* W1b  = d_in[3];
    const void* b1   = d_in[4];
    const void* g1   = d_in[5];
    const void* be1  = d_in[6];
    const void* W2   = d_in[7];
    const void* b2   = d_in[8];
    const void* gn   = d_in[9];
    const void* bnb  = d_in[10];
    const void* fcw  = d_in[11];
    const void* fcb  = d_in[12];
    const void* fc2w = d_in[13];
    const void* fc2b = d_in[14];
    const int* ei    = (const int*)d_in[15];
    const int* batch = (const int*)d_in[16];

    char* p = (char*)d_ws;
    size_t off = 0;
    u16* zb = (u16*)(p + off); off += align256((size_t)N_NODES * HD * 2);
    u16* hb = (u16*)(p + off); off += align256((size_t)N_NODES * HD * 2);
    u16* wpack = (u16*)(p + off); off += align256((size_t)12 * HD * HD * 2);
    float* biasf = (float*)(p + off); off += align256((size_t)12 * HD * 4);
    float* emb = (float*)(p + off); off += align256((size_t)N_GRAPHS * 256 * 4);
    int* row_ptr = (int*)(p + off); off += align256((size_t)(N_NODES + 1) * 4);
    int* cursor = (int*)(p + off); off += align256((size_t)N_NODES * 4);
    int* col_idx = (int*)(p + off); off += align256((size_t)N_EDGES * 4);
    int* bsum = (int*)(p + off); off += align256((size_t)SB * 4);
    float* statsAll = (float*)(p + off); off += align256((size_t)12 * NREP * 256 * 4);
    int* mode = (int*)(p + off); off += align256(4);

    const int EB = (N_EDGES + 255) / 256;
    const int GBM = (N_NODES + 63) / 64;     // 1563 (BM=64 kernels)
    const int GBG = (N_NODES + 31) / 32;     // 3125 (BM=32 gather kernels)

    detect_kernel<<<1, 256, 0, stream>>>((const u16*)x, mode);

    hipMemsetAsync(cursor, 0, (size_t)N_NODES * 4, stream);
    hipMemsetAsync(statsAll, 0, (size_t)12 * NREP * 256 * 4, stream);
    hist_kernel<<<EB, 256, 0, stream>>>(ei + N_EDGES, cursor);
    scan1_kernel<<<SB, 256, 0, stream>>>(cursor, bsum);
    scan2_kernel<<<1, 512, 0, stream>>>(bsum, row_ptr);
    scan3_kernel<<<SB, 256, 0, stream>>>(cursor, bsum, row_ptr);
    hipMemcpyAsync(cursor, row_ptr, (size_t)N_NODES * 4, hipMemcpyDeviceToDevice, stream);
    fill_kernel<<<EB, 256, 0, stream>>>(ei, ei + N_EDGES, cursor, col_idx);
    pack_w_kernel<<<96, 256, 0, stream>>>(W1a, W1b, W2, mode, wpack);
    pack_b_kernel<<<6, 256, 0, stream>>>(b1, b2, mode, biasf);

    u16* cur = zb;
    u16* oth = hb;
    for (int l = 0; l < NLAYERS; ++l) {
        float* statsA = statsAll + (size_t)l * NREP * 256;
        float* statsB = statsAll + (size_t)(6 + l) * NREP * 256;
        float* statsBprev = statsAll + (size_t)(6 + l - 1) * NREP * 256;
        if (l == 0) {
            // fused gather(x) + gemm1 (no BN on input): x -> cur
            gemm_gather0<<<GBG, 256, 0, stream>>>(x, row_ptr, col_idx, wpack,
                                                  biasf, mode, cur, statsA);
        } else {
            // fused gather+BN(outer,l-1)+lrelu + gemm1: cur -> oth (not in-place)
            gemm_gather<<<GBG, 256, 0, stream>>>(cur, row_ptr, col_idx,
                                                 wpack + (size_t)l * HD * HD,
                                                 biasf + (size_t)l * HD, statsBprev, gn, bnb,
                                                 (size_t)(l - 1) * HD, mode, oth, statsA);
            u16* t = cur; cur = oth; oth = t;
        }
        if (l < NLAYERS - 1) {
            gemm_mfma<1, 1><<<GBM, 256, 0, stream>>>(cur, wpack + (size_t)(6 + l) * HD * HD,
                                                     biasf + (size_t)(6 + l) * HD, statsA, g1, be1,
                                                     (size_t)l * HD, mode, cur, statsB);
        } else {
            gemm_mfma<1, 0><<<GBM, 256, 0, stream>>>(cur, wpack + (size_t)(6 + l) * HD * HD,
                                                     biasf + (size_t)(6 + l) * HD, statsA, g1, be1,
                                                     (size_t)l * HD, mode, cur, nullptr);
        }
    }

    pool_kernel<<<(N_GRAPHS + 3) / 4, 256, 0, stream>>>(cur, batch, mode, emb, d_out);
    final_kernel<<<N_GRAPHS, 64, 0, stream>>>(emb, fcw, fcb, fc2w, fc2b, mode, d_out);
}

// Round 14
// 597.901 us; speedup vs baseline: 3.2723x; 1.0446x over previous
//
#include <hip/hip_runtime.h>
#include <stdint.h>

#define N_NODES 100000
#define N_EDGES 400000
#define N_GRAPHS 2000
#define C_IN 48
#define HD 128
#define NLAYERS 6
#define BN_EPS 1e-5f
#define NSLOPE 0.01f
#define SB 391   // ceil(N_NODES/256)
#define NREP 8   // stats replication factor

typedef uint16_t u16;
typedef uint32_t u32;
typedef short bf16x8 __attribute__((ext_vector_type(8)));
typedef float f32x4 __attribute__((ext_vector_type(4)));

__device__ __forceinline__ float bf2f_lo(u32 v) { return __uint_as_float(v << 16); }
__device__ __forceinline__ float bf2f_hi(u32 v) { return __uint_as_float(v & 0xffff0000u); }
__device__ __forceinline__ float bf2f(u16 h) { return __uint_as_float(((u32)h) << 16); }
__device__ __forceinline__ u16 f2bf(float f) {
    u32 u = __float_as_uint(f);
    u32 r = (u + 0x7fffu + ((u >> 16) & 1u)) >> 16;
    return (u16)r;
}
__device__ __forceinline__ u32 pack2(float a, float b) {
    return (u32)f2bf(a) | ((u32)f2bf(b) << 16);
}
__device__ __forceinline__ float lrelu(float v) { return v >= 0.f ? v : v * NSLOPE; }

// dtype detection: mode=1 -> float inputs are fp32; mode=0 -> bf16.
__global__ __launch_bounds__(256) void detect_kernel(const u16* __restrict__ x, int* __restrict__ mode) {
    __shared__ int flag;
    if (threadIdx.x == 0) flag = 0;
    __syncthreads();
    int local = 0;
    for (int i = threadIdx.x; i < 16384; i += 256) {
        float a = fabsf(bf2f(x[i]));
        if (!(a < 1e4f)) local = 1;
    }
    if (local) flag = 1;
    __syncthreads();
    if (threadIdx.x == 0) mode[0] = flag;
}

// ---------------- CSR build ----------------
__global__ __launch_bounds__(256) void hist_kernel(const int* __restrict__ dst, int* __restrict__ cnt) {
    int e = blockIdx.x * 256 + threadIdx.x;
    if (e < N_EDGES) atomicAdd(&cnt[dst[e]], 1);
}

__global__ __launch_bounds__(256) void scan1_kernel(const int* __restrict__ cnt, int* __restrict__ bsum) {
    __shared__ int s[256];
    const int t = threadIdx.x;
    const int i = blockIdx.x * 256 + t;
    s[t] = (i < N_NODES) ? cnt[i] : 0;
    __syncthreads();
    for (int d = 128; d > 0; d >>= 1) {
        if (t < d) s[t] += s[t + d];
        __syncthreads();
    }
    if (t == 0) bsum[blockIdx.x] = s[0];
}

__global__ __launch_bounds__(512) void scan2_kernel(int* __restrict__ bsum, int* __restrict__ row_ptr) {
    __shared__ int s[SB];
    const int t = threadIdx.x;
    if (t < SB) s[t] = bsum[t];
    __syncthreads();
    if (t == 0) {
        int run = 0;
        for (int b = 0; b < SB; ++b) { int v = s[b]; s[b] = run; run += v; }
        row_ptr[0] = 0;
    }
    __syncthreads();
    if (t < SB) bsum[t] = s[t];
}

__global__ __launch_bounds__(256) void scan3_kernel(const int* __restrict__ cnt, const int* __restrict__ bsum,
                                                    int* __restrict__ row_ptr) {
    __shared__ int s[256];
    const int t = threadIdx.x;
    const int i = blockIdx.x * 256 + t;
    s[t] = (i < N_NODES) ? cnt[i] : 0;
    __syncthreads();
    if (t == 0) {
        int run = bsum[blockIdx.x];
        for (int j = 0; j < 256; ++j) { run += s[j]; s[j] = run; }
    }
    __syncthreads();
    if (i < N_NODES) row_ptr[i + 1] = s[t];
}

__global__ __launch_bounds__(256) void fill_kernel(const int* __restrict__ src, const int* __restrict__ dst,
                                                   int* __restrict__ cursor, int* __restrict__ col_idx) {
    int e = blockIdx.x * 256 + threadIdx.x;
    if (e < N_EDGES) {
        int d = dst[e];
        int slot = atomicAdd(&cursor[d], 1);
        col_idx[slot] = src[e];
    }
}

// ---------------- weight pre-pack into MFMA B-fragment layout (bf16) ----------------
__global__ __launch_bounds__(256) void pack_w_kernel(const void* __restrict__ W1a, const void* __restrict__ W1b,
                                                     const void* __restrict__ W2, const int* __restrict__ mode,
                                                     u16* __restrict__ wpack) {
    const int t = blockIdx.x * 256 + threadIdx.x;  // 12*2048 = 24576
    if (t >= 24576) return;
    const int mat = t >> 11;
    const int r = t & 2047;
    const int l = r & 63;
    const int f = r >> 6;
    const int kb = f >> 3, nt = f & 7;
    const int k0 = kb * 32 + (l >> 4) * 8;
    const int n = nt * 16 + (l & 15);
    const int md = *mode;
    u16 vals[8];
    #pragma unroll
    for (int j = 0; j < 8; ++j) {
        const int k = k0 + j;
        float v;
        if (mat == 0) {
            v = (k < C_IN) ? (md ? ((const float*)W1a)[k * HD + n] : bf2f(((const u16*)W1a)[k * HD + n])) : 0.f;
        } else if (mat < 6) {
            const size_t o = (size_t)(mat - 1) * HD * HD + (size_t)k * HD + n;
            v = md ? ((const float*)W1b)[o] : bf2f(((const u16*)W1b)[o]);
        } else {
            const size_t o = (size_t)(mat - 6) * HD * HD + (size_t)k * HD + n;
            v = md ? ((const float*)W2)[o] : bf2f(((const u16*)W2)[o]);
        }
        vals[j] = f2bf(v);
    }
    uint4 o;
    o.x = (u32)vals[0] | ((u32)vals[1] << 16);
    o.y = (u32)vals[2] | ((u32)vals[3] << 16);
    o.z = (u32)vals[4] | ((u32)vals[5] << 16);
    o.w = (u32)vals[6] | ((u32)vals[7] << 16);
    *reinterpret_cast<uint4*>(wpack + (size_t)t * 8) = o;
}

// ---------------- bias pre-pack to f32 ----------------
__global__ __launch_bounds__(256) void pack_b_kernel(const void* __restrict__ b1, const void* __restrict__ b2,
                                                     const int* __restrict__ mode, float* __restrict__ biasf) {
    const int i = blockIdx.x * 256 + threadIdx.x;  // 12*128
    if (i >= 12 * HD) return;
    const int mat = i >> 7, c = i & 127;
    const int md = *mode;
    float v;
    if (mat < 6) v = md ? ((const float*)b1)[mat * HD + c] : bf2f(((const u16*)b1)[mat * HD + c]);
    else         v = md ? ((const float*)b2)[(mat - 6) * HD + c] : bf2f(((const u16*)b2)[(mat - 6) * HD + c]);
    biasf[i] = v;
}

// ---- shared helper: compute BN coef[256]={A,B} in LDS from replicated raw stats ----
__device__ __forceinline__ void coef_to_lds(float* coefs, const float* __restrict__ instats,
                                            const void* __restrict__ gammav, const void* __restrict__ betav,
                                            size_t gelem, int md, int tid) {
    if (tid < 128) {
        float sm = 0.f, sq = 0.f;
        #pragma unroll
        for (int rep = 0; rep < NREP; ++rep) {
            sm += instats[rep * 256 + tid];
            sq += instats[rep * 256 + 128 + tid];
        }
        const float inv_n = 1.0f / (float)N_NODES;
        const float mean = sm * inv_n;
        const float var = fmaxf(sq * inv_n - mean * mean, 0.f);
        const float rs = rsqrtf(var + BN_EPS);
        const float g  = md ? ((const float*)gammav)[gelem + tid] : bf2f(((const u16*)gammav)[gelem + tid]);
        const float be = md ? ((const float*)betav)[gelem + tid]  : bf2f(((const u16*)betav)[gelem + tid]);
        const float A = g * rs;
        coefs[tid] = A;
        coefs[128 + tid] = be - A * mean;
    }
}

// ---------------- plain MFMA GEMM: BM=32 (3125 blocks for TLP), LDS A-stage ----------------
// TRANS: BN coefs computed in-block, applied while staging. IN-PLACE SAFE (out == A).
// Wave w: rows (w&1)*16..+16, cols (w>>1)*64..+64.
template <int TRANS, int STATS>
__global__ __launch_bounds__(256) void gemm_mfma(const u16* A, const u16* __restrict__ wp,
                                                 const float* __restrict__ biasf,
                                                 const float* __restrict__ instats,
                                                 const void* __restrict__ gammav, const void* __restrict__ betav,
                                                 size_t gelem, const int* __restrict__ mode,
                                                 u16* out, float* __restrict__ stats) {
    __shared__ u16 Asm[32][136];
    __shared__ float sred[2][128];
    __shared__ float sqred[2][128];
    __shared__ float coefs[256];
    const int tid = threadIdx.x;
    const int m0 = blockIdx.x * 32;
    const int rrow = tid >> 4;   // 0..15
    const int seg = tid & 15;

    if (TRANS) {
        coef_to_lds(coefs, instats, gammav, betav, gelem, *mode, tid);
        __syncthreads();
    }

    {
        float cA[8], cB[8];
        if (TRANS) {
            #pragma unroll
            for (int j = 0; j < 8; ++j) {
                cA[j] = coefs[seg * 8 + j];
                cB[j] = coefs[128 + seg * 8 + j];
            }
        }
        uint4 v[2];
        #pragma unroll
        for (int i = 0; i < 2; ++i) {
            const int gm = m0 + i * 16 + rrow;
            if (gm < N_NODES) v[i] = *reinterpret_cast<const uint4*>(A + (size_t)gm * HD + seg * 8);
            else { v[i].x = 0; v[i].y = 0; v[i].z = 0; v[i].w = 0; }
        }
        #pragma unroll
        for (int i = 0; i < 2; ++i) {
            uint4 o = v[i];
            if (TRANS) {
                u32 w[4] = {o.x, o.y, o.z, o.w};
                #pragma unroll
                for (int p = 0; p < 4; ++p) {
                    const float lo = lrelu(cA[2 * p] * bf2f_lo(w[p]) + cB[2 * p]);
                    const float hi = lrelu(cA[2 * p + 1] * bf2f_hi(w[p]) + cB[2 * p + 1]);
                    w[p] = pack2(lo, hi);
                }
                o.x = w[0]; o.y = w[1]; o.z = w[2]; o.w = w[3];
            }
            *reinterpret_cast<uint4*>(&Asm[i * 16 + rrow][seg * 8]) = o;
        }
    }
    __syncthreads();

    const int wave = tid >> 6, lane = tid & 63;
    const int quad = lane >> 4, lx = lane & 15;
    const int rowhalf = wave & 1;
    const int colhalf = wave >> 1;
    const int wrow = rowhalf * 16;
    f32x4 acc[4] = {};
    #pragma unroll
    for (int kb = 0; kb < 4; ++kb) {
        bf16x8 bfr[4];
        #pragma unroll
        for (int nt = 0; nt < 4; ++nt)
            bfr[nt] = *reinterpret_cast<const bf16x8*>(wp + (((size_t)(kb * 8 + colhalf * 4 + nt) * 64 + lane) << 3));
        const bf16x8 af = *reinterpret_cast<const bf16x8*>(&Asm[wrow + lx][kb * 32 + quad * 8]);
        #pragma unroll
        for (int nt = 0; nt < 4; ++nt)
            acc[nt] = __builtin_amdgcn_mfma_f32_16x16x32_bf16(af, bfr[nt], acc[nt], 0, 0, 0);
    }

    const int mrow0 = m0 + wrow;
    #pragma unroll
    for (int nt = 0; nt < 4; ++nt) {
        const int n = colhalf * 64 + nt * 16 + lx;
        const float bj = biasf[n];
        float s = 0.f, q = 0.f;
        #pragma unroll
        for (int r = 0; r < 4; ++r) {
            const int m = mrow0 + quad * 4 + r;
            if (m < N_NODES) {
                const float v = acc[nt][r] + bj;
                out[(size_t)m * HD + n] = f2bf(v);
                if (STATS) { s += v; q += v * v; }
            }
        }
        if (STATS) {
            s += __shfl_xor(s, 16); s += __shfl_xor(s, 32);
            q += __shfl_xor(q, 16); q += __shfl_xor(q, 32);
            if (quad == 0) { sred[rowhalf][n] = s; sqred[rowhalf][n] = q; }
        }
    }
    if (STATS) {
        __syncthreads();
        float* sdst = stats + (size_t)(blockIdx.x & (NREP - 1)) * 256;
        if (tid < 128) {
            atomicAdd(&sdst[tid], sred[0][tid] + sred[1][tid]);
        } else if (tid < 256) {
            const int c2 = tid - 128;
            atomicAdd(&sdst[128 + c2], sqred[0][c2] + sqred[1][c2]);
        }
    }
}

// ---------------- FUSED gather+BN+lrelu GEMM — BM=16 (6250 blocks) ----------------
// One node per staging thread (minimal straggler tail); wave w covers cols w*32..+32.
// NOT in-place. STATS on.
__global__ __launch_bounds__(256) void gemm_gather(const u16* __restrict__ U, const int* __restrict__ row_ptr,
                                                   const int* __restrict__ col_idx, const u16* __restrict__ wp,
                                                   const float* __restrict__ biasf,
                                                   const float* __restrict__ instats,
                                                   const void* __restrict__ gammav, const void* __restrict__ betav,
                                                   size_t gelem, const int* __restrict__ mode,
                                                   u16* __restrict__ out, float* __restrict__ stats) {
    __shared__ u16 Asm[16][136];
    __shared__ float sred[128];
    __shared__ float sqred[128];
    __shared__ float coefs[256];
    const int tid = threadIdx.x;
    const int m0 = blockIdx.x * 16;
    const int rrow = tid >> 4;   // 0..15 = row
    const int seg = tid & 15;

    coef_to_lds(coefs, instats, gammav, betav, gelem, *mode, tid);
    __syncthreads();

    {
        float cA[8], cB[8];
        #pragma unroll
        for (int j = 0; j < 8; ++j) {
            cA[j] = coefs[seg * 8 + j];
            cB[j] = coefs[128 + seg * 8 + j];
        }
        const int gm = m0 + rrow;
        float a[8];
        #pragma unroll
        for (int j = 0; j < 8; ++j) a[j] = 0.f;
        if (gm < N_NODES) {
            const uint4 v = *reinterpret_cast<const uint4*>(U + (size_t)gm * HD + seg * 8);
            const u32 w[4] = {v.x, v.y, v.z, v.w};
            #pragma unroll
            for (int p = 0; p < 4; ++p) {
                a[2 * p]     = lrelu(cA[2 * p] * bf2f_lo(w[p]) + cB[2 * p]);
                a[2 * p + 1] = lrelu(cA[2 * p + 1] * bf2f_hi(w[p]) + cB[2 * p + 1]);
            }
            const int s = row_ptr[gm];
            const int deg = row_ptr[gm + 1] - s;
            for (int t = 0; t < deg; t += 2) {
                const int id0 = col_idx[s + t];
                const bool h1 = (t + 1) < deg;
                const int id1 = h1 ? col_idx[s + t + 1] : 0;
                const uint4 r0 = *reinterpret_cast<const uint4*>(U + (size_t)id0 * HD + seg * 8);
                uint4 r1; r1.x = r1.y = r1.z = r1.w = 0;
                if (h1) r1 = *reinterpret_cast<const uint4*>(U + (size_t)id1 * HD + seg * 8);
                const u32 w0[4] = {r0.x, r0.y, r0.z, r0.w};
                const u32 w1[4] = {r1.x, r1.y, r1.z, r1.w};
                #pragma unroll
                for (int p = 0; p < 4; ++p) {
                    a[2 * p]     += lrelu(cA[2 * p] * bf2f_lo(w0[p]) + cB[2 * p]);
                    a[2 * p + 1] += lrelu(cA[2 * p + 1] * bf2f_hi(w0[p]) + cB[2 * p + 1]);
                    if (h1) {
                        a[2 * p]     += lrelu(cA[2 * p] * bf2f_lo(w1[p]) + cB[2 * p]);
                        a[2 * p + 1] += lrelu(cA[2 * p + 1] * bf2f_hi(w1[p]) + cB[2 * p + 1]);
                    }
                }
            }
        }
        uint4 o;
        o.x = pack2(a[0], a[1]); o.y = pack2(a[2], a[3]);
        o.z = pack2(a[4], a[5]); o.w = pack2(a[6], a[7]);
        *reinterpret_cast<uint4*>(&Asm[rrow][seg * 8]) = o;
    }
    __syncthreads();

    // MFMA: wave w covers cols w*32..+32 of the 16-row tile
    const int wave = tid >> 6, lane = tid & 63;
    const int quad = lane >> 4, lx = lane & 15;
    f32x4 acc[2] = {};
    #pragma unroll
    for (int kb = 0; kb < 4; ++kb) {
        bf16x8 bfr[2];
        #pragma unroll
        for (int nt = 0; nt < 2; ++nt)
            bfr[nt] = *reinterpret_cast<const bf16x8*>(wp + (((size_t)(kb * 8 + wave * 2 + nt) * 64 + lane) << 3));
        const bf16x8 af = *reinterpret_cast<const bf16x8*>(&Asm[lx][kb * 32 + quad * 8]);
        #pragma unroll
        for (int nt = 0; nt < 2; ++nt)
            acc[nt] = __builtin_amdgcn_mfma_f32_16x16x32_bf16(af, bfr[nt], acc[nt], 0, 0, 0);
    }

    #pragma unroll
    for (int nt = 0; nt < 2; ++nt) {
        const int n = wave * 32 + nt * 16 + lx;
        const float bj = biasf[n];
        float s = 0.f, q = 0.f;
        #pragma unroll
        for (int r = 0; r < 4; ++r) {
            const int m = m0 + quad * 4 + r;
            if (m < N_NODES) {
                const float v = acc[nt][r] + bj;
                out[(size_t)m * HD + n] = f2bf(v);
                s += v; q += v * v;
            }
        }
        s += __shfl_xor(s, 16); s += __shfl_xor(s, 32);
        q += __shfl_xor(q, 16); q += __shfl_xor(q, 32);
        if (quad == 0) { sred[n] = s; sqred[n] = q; }  // cols partitioned across waves: no race
    }
    __syncthreads();
    float* sdst = stats + (size_t)(blockIdx.x & (NREP - 1)) * 256;
    if (tid < 128) {
        atomicAdd(&sdst[tid], sred[tid]);
    } else if (tid < 256) {
        const int c2 = tid - 128;
        atomicAdd(&sdst[128 + c2], sqred[c2]);
    }
}

// ---------------- FUSED layer-0: gather over x (C_IN cols, no BN) + GEMM — BM=16 ----------------
__global__ __launch_bounds__(256) void gemm_gather0(const void* __restrict__ xv, const int* __restrict__ row_ptr,
                                                    const int* __restrict__ col_idx, const u16* __restrict__ wp,
                                                    const float* __restrict__ biasf, const int* __restrict__ mode,
                                                    u16* __restrict__ out, float* __restrict__ stats) {
    __shared__ u16 Asm[16][136];
    __shared__ float sred[128];
    __shared__ float sqred[128];
    const int tid = threadIdx.x;
    const int m0 = blockIdx.x * 16;
    const int rrow = tid >> 4;
    const int seg = tid & 15;          // segs 0..5 carry data (48 cols), 6..15 zero
    const int md = *mode;
    const bool act = seg < 6;

    {
        const int gm = m0 + rrow;
        float a[8];
        #pragma unroll
        for (int j = 0; j < 8; ++j) a[j] = 0.f;
        if (gm < N_NODES && act) {
            if (md) {
                const float* xf = (const float*)xv + (size_t)gm * C_IN + seg * 8;
                const float4 v0 = reinterpret_cast<const float4*>(xf)[0];
                const float4 v1 = reinterpret_cast<const float4*>(xf)[1];
                a[0] = v0.x; a[1] = v0.y; a[2] = v0.z; a[3] = v0.w;
                a[4] = v1.x; a[5] = v1.y; a[6] = v1.z; a[7] = v1.w;
            } else {
                const uint4 v = *reinterpret_cast<const uint4*>((const u16*)xv + (size_t)gm * C_IN + seg * 8);
                const u32 w[4] = {v.x, v.y, v.z, v.w};
                #pragma unroll
                for (int p = 0; p < 4; ++p) { a[2 * p] = bf2f_lo(w[p]); a[2 * p + 1] = bf2f_hi(w[p]); }
            }
        }
        if (gm < N_NODES) {
            const int s = row_ptr[gm];
            const int deg = row_ptr[gm + 1] - s;
            for (int t = 0; t < deg; t += 2) {
                const int id0 = col_idx[s + t];
                const bool h1 = (t + 1) < deg;
                const int id1 = h1 ? col_idx[s + t + 1] : 0;
                if (act) {
                    if (md) {
                        const float* p0 = (const float*)xv + (size_t)id0 * C_IN + seg * 8;
                        const float4 u0 = reinterpret_cast<const float4*>(p0)[0];
                        const float4 u1 = reinterpret_cast<const float4*>(p0)[1];
                        a[0] += u0.x; a[1] += u0.y; a[2] += u0.z; a[3] += u0.w;
                        a[4] += u1.x; a[5] += u1.y; a[6] += u1.z; a[7] += u1.w;
                        if (h1) {
                            const float* p1 = (const float*)xv + (size_t)id1 * C_IN + seg * 8;
                            const float4 t0 = reinterpret_cast<const float4*>(p1)[0];
                            const float4 t1 = reinterpret_cast<const float4*>(p1)[1];
                            a[0] += t0.x; a[1] += t0.y; a[2] += t0.z; a[3] += t0.w;
                            a[4] += t1.x; a[5] += t1.y; a[6] += t1.z; a[7] += t1.w;
                        }
                    } else {
                        const uint4 r0 = *reinterpret_cast<const uint4*>((const u16*)xv + (size_t)id0 * C_IN + seg * 8);
                        const u32 w0[4] = {r0.x, r0.y, r0.z, r0.w};
                        #pragma unroll
                        for (int p = 0; p < 4; ++p) { a[2 * p] += bf2f_lo(w0[p]); a[2 * p + 1] += bf2f_hi(w0[p]); }
                        if (h1) {
                            const uint4 r1 = *reinterpret_cast<const uint4*>((const u16*)xv + (size_t)id1 * C_IN + seg * 8);
                            const u32 w1[4] = {r1.x, r1.y, r1.z, r1.w};
                            #pragma unroll
                            for (int p = 0; p < 4; ++p) { a[2 * p] += bf2f_lo(w1[p]); a[2 * p + 1] += bf2f_hi(w1[p]); }
                        }
                    }
                }
            }
        }
        uint4 o;
        o.x = pack2(a[0], a[1]); o.y = pack2(a[2], a[3]);
        o.z = pack2(a[4], a[5]); o.w = pack2(a[6], a[7]);
        *reinterpret_cast<uint4*>(&Asm[rrow][seg * 8]) = o;
    }
    __syncthreads();

    const int wave = tid >> 6, lane = tid & 63;
    const int quad = lane >> 4, lx = lane & 15;
    f32x4 acc[2] = {};
    #pragma unroll
    for (int kb = 0; kb < 4; ++kb) {
        bf16x8 bfr[2];
        #pragma unroll
        for (int nt = 0; nt < 2; ++nt)
            bfr[nt] = *reinterpret_cast<const bf16x8*>(wp + (((size_t)(kb * 8 + wave * 2 + nt) * 64 + lane) << 3));
        const bf16x8 af = *reinterpret_cast<const bf16x8*>(&Asm[lx][kb * 32 + quad * 8]);
        #pragma unroll
        for (int nt = 0; nt < 2; ++nt)
            acc[nt] = __builtin_amdgcn_mfma_f32_16x16x32_bf16(af, bfr[nt], acc[nt], 0, 0, 0);
    }

    #pragma unroll
    for (int nt = 0; nt < 2; ++nt) {
        const int n = wave * 32 + nt * 16 + lx;
        const float bj = biasf[n];
        float s = 0.f, q = 0.f;
        #pragma unroll
        for (int r = 0; r < 4; ++r) {
            const int m = m0 + quad * 4 + r;
            if (m < N_NODES) {
                const float v = acc[nt][r] + bj;
                out[(size_t)m * HD + n] = f2bf(v);
                s += v; q += v * v;
            }
        }
        s += __shfl_xor(s, 16); s += __shfl_xor(s, 32);
        q += __shfl_xor(q, 16); q += __shfl_xor(q, 32);
        if (quad == 0) { sred[n] = s; sqred[n] = q; }
    }
    __syncthreads();
    float* sdst = stats + (size_t)(blockIdx.x & (NREP - 1)) * 256;
    if (tid < 128) {
        atomicAdd(&sdst[tid], sred[tid]);
    } else if (tid < 256) {
        const int c2 = tid - 128;
        atomicAdd(&sdst[128 + c2], sqred[c2]);
    }
}

// ---------------- pooling: wave per graph, uint4 row loads, quad-parallel rows ----------------
__global__ __launch_bounds__(256) void pool_kernel(const u16* __restrict__ hf, const int* __restrict__ batch,
                                                   const int* __restrict__ mode, float* __restrict__ emb,
                                                   void* __restrict__ outv) {
    const int wave = threadIdx.x >> 6, lane = threadIdx.x & 63;
    const int g = blockIdx.x * 4 + wave;
    if (g >= N_GRAPHS) return;
    const int md = *mode;
    const int quad = lane >> 4, c = lane & 15;
    int lo = 0, hi = N_NODES;
    while (lo < hi) { int m = (lo + hi) >> 1; if (batch[m] < g) lo = m + 1; else hi = m; }
    const int s = lo;
    hi = N_NODES;
    while (lo < hi) { int m = (lo + hi) >> 1; if (batch[m] < g + 1) lo = m + 1; else hi = m; }
    const int e = lo;
    const int cnt = e - s;
    float sum[8], mx[8];
    #pragma unroll
    for (int j = 0; j < 8; ++j) { sum[j] = 0.f; mx[j] = -INFINITY; }
    for (int n = s + quad; n < e; n += 4) {
        const uint4 v = *reinterpret_cast<const uint4*>(hf + (size_t)n * HD + c * 8);
        const u32 w[4] = {v.x, v.y, v.z, v.w};
        #pragma unroll
        for (int p = 0; p < 4; ++p) {
            const float f0 = bf2f_lo(w[p]), f1 = bf2f_hi(w[p]);
            sum[2 * p] += f0; sum[2 * p + 1] += f1;
            mx[2 * p] = fmaxf(mx[2 * p], f0); mx[2 * p + 1] = fmaxf(mx[2 * p + 1], f1);
        }
    }
    #pragma unroll
    for (int j = 0; j < 8; ++j) {
        sum[j] += __shfl_xor(sum[j], 16); sum[j] += __shfl_xor(sum[j], 32);
        mx[j] = fmaxf(mx[j], __shfl_xor(mx[j], 16));
        mx[j] = fmaxf(mx[j], __shfl_xor(mx[j], 32));
    }
    if (quad == 0) {
        const float invc = 1.0f / (float)max(cnt, 1);
        const size_t base = (size_t)N_GRAPHS * 3 + (size_t)g * 256;
        #pragma unroll
        for (int j = 0; j < 8; ++j) {
            const float mean = sum[j] * invc;
            const float m2 = (cnt == 0) ? 0.f : mx[j];
            const int col = c * 8 + j;
            emb[(size_t)g * 256 + col] = mean;
            emb[(size_t)g * 256 + 128 + col] = m2;
            if (md) {
                ((float*)outv)[base + col] = mean;
                ((float*)outv)[base + 128 + col] = m2;
            } else {
                ((u16*)outv)[base + col] = f2bf(mean);
                ((u16*)outv)[base + 128 + col] = f2bf(m2);
            }
        }
    }
}

__global__ __launch_bounds__(64) void final_kernel(const float* __restrict__ emb, const void* __restrict__ fcwv,
                                                   const void* __restrict__ fcbv, const void* __restrict__ fc2wv,
                                                   const void* __restrict__ fc2bv, const int* __restrict__ mode,
                                                   void* __restrict__ outv) {
    __shared__ float es[256];
    __shared__ float hs[64];
    const int g = blockIdx.x, t = threadIdx.x;
    const int md = *mode;
    reinterpret_cast<float4*>(es)[t] = reinterpret_cast<const float4*>(emb + (size_t)g * 256)[t];
    __syncthreads();
    float acc = md ? ((const float*)fcbv)[t] : bf2f(((const u16*)fcbv)[t]);
    if (md) {
        const float* w = (const float*)fcwv;
        #pragma unroll 8
        for (int k = 0; k < 256; ++k) acc += es[k] * w[k * 64 + t];
    } else {
        const u16* w = (const u16*)fcwv;
        #pragma unroll 8
        for (int k = 0; k < 256; ++k) acc += es[k] * bf2f(w[k * 64 + t]);
    }
    hs[t] = lrelu(acc);
    __syncthreads();
    if (t < 3) {
        float o = md ? ((const float*)fc2bv)[t] : bf2f(((const u16*)fc2bv)[t]);
        if (md) {
            const float* w = (const float*)fc2wv;
            #pragma unroll 8
            for (int j = 0; j < 64; ++j) o += hs[j] * w[j * 3 + t];
            ((float*)outv)[(size_t)g * 3 + t] = o;
        } else {
            const u16* w = (const u16*)fc2wv;
            #pragma unroll 8
            for (int j = 0; j < 64; ++j) o += hs[j] * bf2f(w[j * 3 + t]);
            ((u16*)outv)[(size_t)g * 3 + t] = f2bf(o);
        }
    }
}

// ---------------- launch ----------------
static inline size_t align256(size_t x) { return (x + 255) & ~(size_t)255; }

extern "C" void kernel_launch(void* const* d_in, const int* in_sizes, int n_in,
                              void* d_out, int out_size, void* d_ws, size_t ws_size,
                              hipStream_t stream) {
    (void)in_sizes; (void)n_in; (void)out_size; (void)ws_size;
    const void* x    = d_in[0];
    const void* W1a  = d_in[2];
    const void* W1b  = d_in[3];
    const void* b1   = d_in[4];
    const void* g1   = d_in[5];
    const void* be1  = d_in[6];
    const void* W2   = d_in[7];
    const void* b2   = d_in[8];
    const void* gn   = d_in[9];
    const void* bnb  = d_in[10];
    const void* fcw  = d_in[11];
    const void* fcb  = d_in[12];
    const void* fc2w = d_in[13];
    const void* fc2b = d_in[14];
    const int* ei    = (const int*)d_in[15];
    const int* batch = (const int*)d_in[16];

    char* p = (char*)d_ws;
    size_t off = 0;
    u16* zb = (u16*)(p + off); off += align256((size_t)N_NODES * HD * 2);
    u16* hb = (u16*)(p + off); off += align256((size_t)N_NODES * HD * 2);
    u16* wpack = (u16*)(p + off); off += align256((size_t)12 * HD * HD * 2);
    float* biasf = (float*)(p + off); off += align256((size_t)12 * HD * 4);
    float* emb = (float*)(p + off); off += align256((size_t)N_GRAPHS * 256 * 4);
    int* row_ptr = (int*)(p + off); off += align256((size_t)(N_NODES + 1) * 4);
    int* cursor = (int*)(p + off); off += align256((size_t)N_NODES * 4);
    int* col_idx = (int*)(p + off); off += align256((size_t)N_EDGES * 4);
    int* bsum = (int*)(p + off); off += align256((size_t)SB * 4);
    float* statsAll = (float*)(p + off); off += align256((size_t)12 * NREP * 256 * 4);
    int* mode = (int*)(p + off); off += align256(4);

    const int EB = (N_EDGES + 255) / 256;
    const int GBM = (N_NODES + 31) / 32;     // 3125 (BM=32 plain gemm)
    const int GBG = (N_NODES + 15) / 16;     // 6250 (BM=16 gather kernels)

    detect_kernel<<<1, 256, 0, stream>>>((const u16*)x, mode);

    hipMemsetAsync(cursor, 0, (size_t)N_NODES * 4, stream);
    hipMemsetAsync(statsAll, 0, (size_t)12 * NREP * 256 * 4, stream);
    hist_kernel<<<EB, 256, 0, stream>>>(ei + N_EDGES, cursor);
    scan1_kernel<<<SB, 256, 0, stream>>>(cursor, bsum);
    scan2_kernel<<<1, 512, 0, stream>>>(bsum, row_ptr);
    scan3_kernel<<<SB, 256, 0, stream>>>(cursor, bsum, row_ptr);
    hipMemcpyAsync(cursor, row_ptr, (size_t)N_NODES * 4, hipMemcpyDeviceToDevice, stream);
    fill_kernel<<<EB, 256, 0, stream>>>(ei, ei + N_EDGES, cursor, col_idx);
    pack_w_kernel<<<96, 256, 0, stream>>>(W1a, W1b, W2, mode, wpack);
    pack_b_kernel<<<6, 256, 0, stream>>>(b1, b2, mode, biasf);

    u16* cur = zb;
    u16* oth = hb;
    for (int l = 0; l < NLAYERS; ++l) {
        float* statsA = statsAll + (size_t)l * NREP * 256;
        float* statsB = statsAll + (size_t)(6 + l) * NREP * 256;
        float* statsBprev = statsAll + (size_t)(6 + l - 1) * NREP * 256;
        if (l == 0) {
            // fused gather(x) + gemm1 (no BN on input): x -> cur
            gemm_gather0<<<GBG, 256, 0, stream>>>(x, row_ptr, col_idx, wpack,
                                                  biasf, mode, cur, statsA);
        } else {
            // fused gather+BN(outer,l-1)+lrelu + gemm1: cur -> oth (not in-place)
            gemm_gather<<<GBG, 256, 0, stream>>>(cur, row_ptr, col_idx,
                                                 wpack + (size_t)l * HD * HD,
                                                 biasf + (size_t)l * HD, statsBprev, gn, bnb,
                                                 (size_t)(l - 1) * HD, mode, oth, statsA);
            u16* t = cur; cur = oth; oth = t;
        }
        if (l < NLAYERS - 1) {
            gemm_mfma<1, 1><<<GBM, 256, 0, stream>>>(cur, wpack + (size_t)(6 + l) * HD * HD,
                                                     biasf + (size_t)(6 + l) * HD, statsA, g1, be1,
                                                     (size_t)l * HD, mode, cur, statsB);
        } else {
            gemm_mfma<1, 0><<<GBM, 256, 0, stream>>>(cur, wpack + (size_t)(6 + l) * HD * HD,
                                                     biasf + (size_t)(6 + l) * HD, statsA, g1, be1,
                                                     (size_t)l * HD, mode, cur, nullptr);
        }
    }

    pool_kernel<<<(N_GRAPHS + 3) / 4, 256, 0, stream>>>(cur, batch, mode, emb, d_out);
    final_kernel<<<N_GRAPHS, 64, 0, stream>>>(emb, fcw, fcb, fc2w, fc2b, mode, d_out);
}